// Round 4
// baseline (974.315 us; speedup 1.0000x reference)
//
#include <hip/hip_runtime.h>

typedef __attribute__((ext_vector_type(8))) short short8;
typedef __attribute__((ext_vector_type(4))) float f32x4;

static __device__ __forceinline__ float b2f(unsigned short u) {
  return __uint_as_float(((unsigned int)u) << 16);
}
static __device__ __forceinline__ unsigned short f2bs(float f) {
  unsigned int u = __float_as_uint(f);
  u = u + 0x7FFFu + ((u >> 16) & 1u);   // RNE (no NaN inputs here)
  return (unsigned short)(u >> 16);
}

// async global->LDS DMA, 16B per lane; LDS dest = wave-uniform base + lane*16
static __device__ __forceinline__ void gload16(const void* g, void* l) {
  __builtin_amdgcn_global_load_lds(
      (const __attribute__((address_space(1))) void*)g,
      (__attribute__((address_space(3))) void*)l, 16, 0, 0);
}

enum { EPI_F32_SUMSQ = 0, EPI_BF16_SUMSQ = 1, EPI_BF16 = 2, EPI_F32_RESID = 3 };

// C[M,N] = A[M,K] @ B[N,K]^T (both K-contiguous). bf16 MFMA 16x16x32.
// BM x BN tile, BK=64, 4 waves (2x2), wave tile (BM/2)x(BN/2).
// Double-buffered LDS, ONE barrier per K-step. B (and A when bf16) staged via
// global_load_lds with pre-swizzled SOURCE (linear LDS dest, swizzled read).
// A f32 path: reg-stage + fused bf16 convert, ds_write overlapping MFMA.
template<int BM, int BN, bool AF32, int EPI, bool XCD1D>
__global__ __launch_bounds__(256, 2) void gemm_bt(
    const void* __restrict__ Av, const short* __restrict__ B, void* __restrict__ Cv,
    const float* __restrict__ bias, const float* __restrict__ resid,
    float* __restrict__ sumsq,
    long lda, long ldb, long ldc, int K, float escale,
    long aZ, long bZ, long cZ, int biasZ, int ncolb)
{
  constexpr int BK = 64;
  constexpr int WM = BM / 2, WN = BN / 2, MR = WM / 16, NR = WN / 16;
  __shared__ __align__(16) short As[2][BM * BK];
  __shared__ __align__(16) short Bs[2][BN * BK];
  const int t = threadIdx.x;
  const int zb = blockIdx.z;
  long bxc, byp;
  if constexpr (XCD1D) {
    int bid = blockIdx.x;
    int per = gridDim.x >> 3;       // blocks per XCD (grid % 8 == 0)
    int ppx = per / ncolb;          // row panels per XCD
    int xcd = bid & 7, j = bid >> 3;
    byp = (long)xcd * ppx + j / ncolb;
    bxc = j % ncolb;
  } else {
    byp = blockIdx.x; bxc = blockIdx.y;
  }
  const long row0 = byp * BM;
  const long col0 = bxc * BN;
  const int wave = t >> 6, lane = t & 63;
  const int wr = wave >> 1, wc = wave & 1;
  const int lr = lane & 15, lg = lane >> 4;
  const short* Bz = B + (size_t)zb * bZ;
  const int lrow8 = lane >> 3;             // row within 8-row chunk
  const int lgran = (lane & 7) ^ lrow8;    // pre-swizzled source granule

  float4 pa[BM / 32][2];   // fp32 A staging (AF32 only)

  auto loadA_f32 = [&](int k0) {
    #pragma unroll
    for (int r = 0; r < BM / 32; ++r) {
      int e = r * 2048 + t * 8; int row = e >> 6, col = e & 63;
      const float* src = (const float*)Av + (size_t)zb * aZ +
                         (size_t)(row0 + row) * lda + k0 + col;
      pa[r][0] = *(const float4*)src;
      pa[r][1] = *(const float4*)(src + 4);
    }
  };
  auto writeA_f32 = [&](int buf) {
    #pragma unroll
    for (int r = 0; r < BM / 32; ++r) {
      int e = r * 2048 + t * 8; int row = e >> 6, col = e & 63;
      short8 o;
      o[0] = (short)f2bs(pa[r][0].x); o[1] = (short)f2bs(pa[r][0].y);
      o[2] = (short)f2bs(pa[r][0].z); o[3] = (short)f2bs(pa[r][0].w);
      o[4] = (short)f2bs(pa[r][1].x); o[5] = (short)f2bs(pa[r][1].y);
      o[6] = (short)f2bs(pa[r][1].z); o[7] = (short)f2bs(pa[r][1].w);
      *(short8*)&As[buf][row * 64 + (col ^ ((row & 7) << 3))] = o;
    }
  };
  auto dmaA = [&](int buf, int k0) {   // bf16 A via DMA, pre-swizzled source
    const short* Az = (const short*)Av + (size_t)zb * aZ;
    #pragma unroll
    for (int i = 0; i < BM / 32; ++i) {
      int c = wave * (BM / 32) + i;    // 1KB chunk = 8 rows
      gload16(Az + (size_t)(row0 + c * 8 + lrow8) * lda + k0 + lgran * 8,
              &As[buf][c * 512]);
    }
  };
  auto dmaB = [&](int buf, int k0) {
    #pragma unroll
    for (int i = 0; i < BN / 32; ++i) {
      int c = wave * (BN / 32) + i;
      gload16(Bz + (size_t)(col0 + c * 8 + lrow8) * ldb + k0 + lgran * 8,
              &Bs[buf][c * 512]);
    }
  };

  const f32x4 zero4 = {0.f, 0.f, 0.f, 0.f};
  f32x4 acc[MR][NR];
  #pragma unroll
  for (int m = 0; m < MR; ++m)
    #pragma unroll
    for (int n = 0; n < NR; ++n) acc[m][n] = zero4;

  // prologue: stage tile 0 into buf 0
  if constexpr (AF32) loadA_f32(0); else dmaA(0, 0);
  dmaB(0, 0);
  if constexpr (AF32) writeA_f32(0);
  __syncthreads();   // drains DMA (vmcnt0) + LDS writes

  const int nk = K / BK;
  for (int kt = 0; kt < nk; ++kt) {
    const int cur = kt & 1;
    if (kt + 1 < nk) {            // issue next tile into other buffer
      dmaB(cur ^ 1, (kt + 1) * BK);
      if constexpr (AF32) loadA_f32((kt + 1) * BK);
      else dmaA(cur ^ 1, (kt + 1) * BK);
    }
    #pragma unroll
    for (int kk = 0; kk < 2; ++kk) {
      short8 a[MR], b[NR];
      #pragma unroll
      for (int m = 0; m < MR; ++m) {
        int row = wr * WM + m * 16 + lr, col = kk * 32 + lg * 8;
        a[m] = *(const short8*)&As[cur][row * 64 + (col ^ ((row & 7) << 3))];
      }
      #pragma unroll
      for (int n = 0; n < NR; ++n) {
        int row = wc * WN + n * 16 + lr, col = kk * 32 + lg * 8;
        b[n] = *(const short8*)&Bs[cur][row * 64 + (col ^ ((row & 7) << 3))];
      }
      #pragma unroll
      for (int m = 0; m < MR; ++m)
        #pragma unroll
        for (int n = 0; n < NR; ++n)
          acc[m][n] = __builtin_amdgcn_mfma_f32_16x16x32_bf16(a[m], b[n], acc[m][n], 0, 0, 0);
    }
    if constexpr (AF32) { if (kt + 1 < nk) writeA_f32(cur ^ 1); }  // overlaps MFMA
    __syncthreads();   // next buffer ready (DMA drained), this buffer free
  }

  const float* biasz = bias ? (bias + (size_t)zb * biasZ) : nullptr;
  float* Cf = (float*)Cv;
  unsigned short* Cb = (unsigned short*)Cv;
  #pragma unroll
  for (int m = 0; m < MR; ++m) {
    #pragma unroll
    for (int i = 0; i < 4; ++i) {
      long row = row0 + wr * WM + m * 16 + lg * 4 + i;
      float sq = 0.f;
      #pragma unroll
      for (int n = 0; n < NR; ++n) {
        long col = col0 + wc * WN + n * 16 + lr;
        float v = acc[m][n][i];
        if (biasz) v += biasz[col];
        v *= escale;
        size_t ci = (size_t)zb * cZ + (size_t)row * ldc + col;
        if constexpr (EPI == EPI_F32_RESID) {
          v += resid[(size_t)row * ldc + col];
          Cf[ci] = v;
        } else if constexpr (EPI == EPI_F32_SUMSQ) {
          Cf[ci] = v;
        } else {
          Cb[ci] = f2bs(v);
        }
        sq += v * v;
      }
      if constexpr (EPI == EPI_F32_SUMSQ || EPI == EPI_BF16_SUMSQ) {
        #pragma unroll
        for (int off = 1; off < 16; off <<= 1) sq += __shfl_xor(sq, off);
        if (lr == 0) atomicAdd(&sumsq[row], sq);
      }
    }
  }
}

__global__ __launch_bounds__(256) void f2b_kernel(const float* __restrict__ s,
                                                  unsigned short* __restrict__ d, long n) {
  long i = (long)blockIdx.x * 256 + threadIdx.x;
  if (i < n) d[i] = f2bs(s[i]);
}

// WkT[h][n][j] = Wk[h*64+j][n],  Wk = in_proj_w rows 768..1535
__global__ __launch_bounds__(256) void wkT_kernel(const float* __restrict__ ipw,
                                                  unsigned short* __restrict__ d) {
  long i = (long)blockIdx.x * 256 + threadIdx.x;
  if (i < 589824) {
    int h = (int)(i / 49152), r = (int)(i % 49152);
    int nn = r >> 6, j = r & 63;
    d[i] = f2bs(ipw[(size_t)(768 + h * 64 + j) * 768 + nn]);
  }
}

__global__ __launch_bounds__(256) void invnorm_kernel(float* s, int n) {
  int i = blockIdx.x * 256 + threadIdx.x;
  if (i < n) s[i] = 1.f / (sqrtf(s[i]) + 1e-6f);
}

__global__ __launch_bounds__(256) void xqnorm_kernel(const float* __restrict__ raw,
                                                     const float* __restrict__ invn,
                                                     float* __restrict__ xf,
                                                     unsigned short* __restrict__ xb) {
  long i = (long)blockIdx.x * 256 + threadIdx.x;  // 8192*768/4
  long e = i * 4;
  int row = (int)(e / 768);
  float inv = invn[row];
  float4 v = *(const float4*)(raw + e);
  v.x *= inv; v.y *= inv; v.z *= inv; v.w *= inv;
  *(float4*)(xf + e) = v;
  short4 o;
  o.x = (short)f2bs(v.x); o.y = (short)f2bs(v.y);
  o.z = (short)f2bs(v.z); o.w = (short)f2bs(v.w);
  *(short4*)(xb + e) = o;
}

// Per-token fused: S = (qk . z)*invn -> softmax_w -> a = attn*invn -> u = a @ z
// QK^T on MFMA (K=768 split over 4 waves), PV vectorized short8 (conflict-free).
// u may alias qk (qk slice fully staged to LDS before write).
__global__ __launch_bounds__(256) void attn_kernel(
    const unsigned short* __restrict__ z, const unsigned short* __restrict__ qk,
    const float* __restrict__ invn, unsigned short* __restrict__ u)
{
  __shared__ __align__(16) unsigned short zl[16 * 768];
  __shared__ __align__(16) unsigned short ql[16 * 768];  // rows 12..15 unused
  __shared__ float sc[3][256];
  __shared__ float al[256];
  __shared__ float il[16];
  const int t = threadIdx.x;
  const long m = blockIdx.x;
  const int wv = t >> 6, lane = t & 63;
  const int lr = lane & 15, lg = lane >> 4;

  // stage (granule-XOR swizzle: 16B granule g stored at g ^ (row&7))
  for (int s = t; s < 1536; s += 256) {
    int row = s / 96, g = s % 96;
    *(short8*)&zl[row * 768 + ((g ^ (row & 7)) << 3)] =
        *(const short8*)(z + m * 12288 + (size_t)s * 8);
  }
  for (int s = t; s < 1152; s += 256) {
    int row = s / 96, g = s % 96;
    *(short8*)&ql[row * 768 + ((g ^ (row & 7)) << 3)] =
        *(const short8*)(qk + m * 9216 + (size_t)s * 8);
  }
  if (t < 16) il[t] = invn[m * 16 + t];
  __syncthreads();

  // QK^T: S[h][w] = sum_k ql[h][k] * zl[w][k]; wave wv covers k in [wv*192, +192)
  f32x4 c = {0.f, 0.f, 0.f, 0.f};
  #pragma unroll
  for (int i = 0; i < 6; ++i) {
    int gb = wv * 24 + i * 4 + lg;   // 16B granule index along K
    short8 a = *(const short8*)&ql[lr * 768 + ((gb ^ (lr & 7)) << 3)];
    short8 b = *(const short8*)&zl[lr * 768 + ((gb ^ (lr & 7)) << 3)];
    c = __builtin_amdgcn_mfma_f32_16x16x32_bf16(a, b, c, 0, 0, 0);
  }
  if (wv > 0) {
    #pragma unroll
    for (int i = 0; i < 4; ++i) sc[wv - 1][(lg * 4 + i) * 16 + lr] = c[i];
  }
  __syncthreads();
  if (wv == 0) {
    // lane holds S[h=lg*4+i][w=lr]; softmax over w (16-lane shfl)
    #pragma unroll
    for (int i = 0; i < 4; ++i) {
      int idx = (lg * 4 + i) * 16 + lr;
      float s = (c[i] + sc[0][idx] + sc[1][idx] + sc[2][idx]) * il[lr];
      float mx = s;
      #pragma unroll
      for (int off = 1; off < 16; off <<= 1) mx = fmaxf(mx, __shfl_xor(mx, off));
      float e = __expf(s - mx);
      float sum = e;
      #pragma unroll
      for (int off = 1; off < 16; off <<= 1) sum += __shfl_xor(sum, off);
      al[idx] = e / sum * il[lr];
    }
  }
  __syncthreads();

  // PV: u[h][d0..d0+8) = sum_w al[h*16+w] * zl[w][d0..]
  for (int s = t; s < 1152; s += 256) {
    int h = s / 96, gd = s % 96;
    float acc[8] = {0.f, 0.f, 0.f, 0.f, 0.f, 0.f, 0.f, 0.f};
    #pragma unroll
    for (int w = 0; w < 16; ++w) {
      float aw = al[h * 16 + w];
      short8 zz = *(const short8*)&zl[w * 768 + ((gd ^ (w & 7)) << 3)];
      #pragma unroll
      for (int j = 0; j < 8; ++j) acc[j] += aw * b2f((unsigned short)zz[j]);
    }
    short8 o;
    #pragma unroll
    for (int j = 0; j < 8; ++j) o[j] = (short)f2bs(acc[j]);
    *(short8*)&u[m * 9216 + (size_t)s * 8] = o;
  }
}

__global__ __launch_bounds__(256) void ln_kernel(const float* __restrict__ R,
                                                 const float* __restrict__ w,
                                                 const float* __restrict__ b,
                                                 float* __restrict__ out) {
  const long row = blockIdx.x;
  const int t = threadIdx.x;
  const float* rr = R + row * 768;
  float v0 = rr[t], v1 = rr[t + 256], v2 = rr[t + 512];
  float s = v0 + v1 + v2;
  #pragma unroll
  for (int off = 1; off < 64; off <<= 1) s += __shfl_xor(s, off);
  __shared__ float ps[4];
  __shared__ float ps2[4];
  const int wave = t >> 6, lane = t & 63;
  if (lane == 0) ps[wave] = s;
  __syncthreads();
  const float mean = (ps[0] + ps[1] + ps[2] + ps[3]) * (1.f / 768.f);
  const float d0 = v0 - mean, d1 = v1 - mean, d2 = v2 - mean;
  float q = d0 * d0 + d1 * d1 + d2 * d2;
  #pragma unroll
  for (int off = 1; off < 64; off <<= 1) q += __shfl_xor(q, off);
  if (lane == 0) ps2[wave] = q;
  __syncthreads();
  const float var = (ps2[0] + ps2[1] + ps2[2] + ps2[3]) * (1.f / 768.f);
  const float rs = rsqrtf(var + 1e-6f);
  float* oo = out + row * 768;
  oo[t]       = d0 * rs * w[t]       + b[t];
  oo[t + 256] = d1 * rs * w[t + 256] + b[t + 256];
  oo[t + 512] = d2 * rs * w[t + 512] + b[t + 512];
}

extern "C" void kernel_launch(void* const* d_in, const int* in_sizes, int n_in,
                              void* d_out, int out_size, void* d_ws, size_t ws_size,
                              hipStream_t stream) {
  const float* x   = (const float*)d_in[0];   // (8,1024,1536)
  const float* y   = (const float*)d_in[1];   // (8,16384,1024)
  const float* Wx  = (const float*)d_in[2];   // (768,1536)
  const float* bx  = (const float*)d_in[3];
  const float* Wy  = (const float*)d_in[4];   // (768,1024)
  const float* by  = (const float*)d_in[5];
  const float* ipw = (const float*)d_in[6];   // (2304,768)
  const float* ipb = (const float*)d_in[7];
  const float* Wo  = (const float*)d_in[8];   // (768,768)
  const float* ob  = (const float*)d_in[9];
  const float* lnw = (const float*)d_in[10];
  const float* lnb = (const float*)d_in[11];
  float* out = (float*)d_out;

  char* ws = (char*)d_ws;
  size_t off = 0;
  auto alloc = [&](size_t bytes) {
    void* p = ws + off;
    off += (bytes + 4095) & ~(size_t)4095;
    return p;
  };
  unsigned short* Wx_b  = (unsigned short*)alloc(768L * 1536 * 2);
  unsigned short* Wy_b  = (unsigned short*)alloc(768L * 1024 * 2);
  unsigned short* Wq_b  = (unsigned short*)alloc(768L * 768 * 2);
  unsigned short* WkT_b = (unsigned short*)alloc(768L * 768 * 2);
  unsigned short* Wv_b  = (unsigned short*)alloc(768L * 768 * 2);
  unsigned short* Wo_b  = (unsigned short*)alloc(768L * 768 * 2);
  float* ssx    = (float*)alloc(8192L * 4);          // sumsq -> invnorm (x path)
  float* ssy    = (float*)alloc(131072L * 4);        // sumsq -> invnorm (y path)
  float* xq_raw = (float*)alloc(8192L * 768 * 4);    // reused as r (residual) later
  float* xq_f   = (float*)alloc(8192L * 768 * 4);
  unsigned short* xq_b = (unsigned short*)alloc(8192L * 768 * 2);
  unsigned short* z_b  = (unsigned short*)alloc(131072L * 768 * 2);
  unsigned short* q_b  = (unsigned short*)alloc(8192L * 768 * 2);
  unsigned short* qk_b = (unsigned short*)alloc(8192L * 9216 * 2);  // also u (aliased)
  unsigned short* o_b  = (unsigned short*)alloc(8192L * 768 * 2);
  float* r_f = xq_raw;
  (void)ws_size; (void)in_sizes; (void)n_in; (void)out_size;

  hipMemsetAsync(ssx, 0, 8192L * 4, stream);
  hipMemsetAsync(ssy, 0, 131072L * 4, stream);

  f2b_kernel<<<4608, 256, 0, stream>>>(Wx, Wx_b, 768L * 1536);
  f2b_kernel<<<3072, 256, 0, stream>>>(Wy, Wy_b, 768L * 1024);
  f2b_kernel<<<2304, 256, 0, stream>>>(ipw, Wq_b, 589824);               // Wq
  wkT_kernel<<<2304, 256, 0, stream>>>(ipw, WkT_b);                      // Wk^T per head
  f2b_kernel<<<2304, 256, 0, stream>>>(ipw + 2 * 589824, Wv_b, 589824);  // Wv
  f2b_kernel<<<2304, 256, 0, stream>>>(Wo, Wo_b, 589824);

  // xq_raw = x @ Wx^T + bx   (+ row sumsq)
  gemm_bt<128, 128, true, EPI_F32_SUMSQ, false><<<dim3(64, 6, 1), 256, 0, stream>>>(
      x, (const short*)Wx_b, xq_raw, bx, nullptr, ssx,
      1536, 1536, 768, 1536, 1.f, 0, 0, 0, 0, 0);
  invnorm_kernel<<<32, 256, 0, stream>>>(ssx, 8192);
  xqnorm_kernel<<<6144, 256, 0, stream>>>(xq_raw, ssx, xq_f, xq_b);

  // z = y @ Wy^T + by (bf16) + row sumsq; XCD-contiguous row panels
  gemm_bt<128, 128, true, EPI_BF16_SUMSQ, true><<<6144, 256, 0, stream>>>(
      y, (const short*)Wy_b, z_b, by, nullptr, ssy,
      1024, 1024, 768, 1024, 1.f, 0, 0, 0, 0, 6);
  invnorm_kernel<<<512, 256, 0, stream>>>(ssy, 131072);

  // q = xq @ Wq^T + bq
  gemm_bt<128, 128, false, EPI_BF16, false><<<dim3(64, 6, 1), 256, 0, stream>>>(
      xq_b, (const short*)Wq_b, q_b, ipb, nullptr, nullptr,
      768, 768, 768, 768, 1.f, 0, 0, 0, 0, 0);

  // qk[m,h,:] = scale * q[m,h*64:+64] @ WkT[h]   (bk dropped: softmax-invariant)
  gemm_bt<128, 128, false, EPI_BF16, false><<<dim3(64, 6, 12), 256, 0, stream>>>(
      q_b, (const short*)WkT_b, qk_b, nullptr, nullptr, nullptr,
      768, 64, 9216, 64, 0.125f, 64, 49152, 768, 0, 0);

  // fused scores/softmax/u  (u overwrites qk slice per token)
  attn_kernel<<<8192, 256, 0, stream>>>(z_b, qk_b, ssy, qk_b);

  // o[:,h*64:+64] = u[:,h,:] @ Wv_h^T + bv_h
  gemm_bt<128, 64, false, EPI_BF16, false><<<dim3(64, 1, 12), 256, 0, stream>>>(
      qk_b, (const short*)Wv_b, o_b, ipb + 1536, nullptr, nullptr,
      9216, 768, 768, 768, 1.f, 768, 49152, 64, 64, 0);

  // r = o @ out_w^T + out_b + xq
  gemm_bt<128, 128, false, EPI_F32_RESID, false><<<dim3(64, 6, 1), 256, 0, stream>>>(
      o_b, (const short*)Wo_b, r_f, ob, xq_f, nullptr,
      768, 768, 768, 768, 1.f, 0, 0, 0, 0, 0);

  ln_kernel<<<8192, 256, 0, stream>>>(r_f, lnw, lnb, out);
}

// Round 6
// 865.111 us; speedup vs baseline: 1.1262x; 1.1262x over previous
//
#include <hip/hip_runtime.h>

typedef __attribute__((ext_vector_type(8))) short short8;
typedef __attribute__((ext_vector_type(4))) float f32x4;

static __device__ __forceinline__ float b2f(unsigned short u) {
  return __uint_as_float(((unsigned int)u) << 16);
}
static __device__ __forceinline__ unsigned short f2bs(float f) {
  unsigned int u = __float_as_uint(f);
  u = u + 0x7FFFu + ((u >> 16) & 1u);   // RNE (no NaN inputs here)
  return (unsigned short)(u >> 16);
}

// async global->LDS DMA, 16B per lane; LDS dest = wave-uniform base + lane*16
static __device__ __forceinline__ void gload16(const void* g, void* l) {
  __builtin_amdgcn_global_load_lds(
      (const __attribute__((address_space(1))) void*)g,
      (__attribute__((address_space(3))) void*)l, 16, 0, 0);
}

enum { EPI_F32_SUMSQ = 0, EPI_BF16_SUMSQ = 1, EPI_BF16 = 2, EPI_F32_RESID = 3 };

// C[M,N] = A[M,K] @ B[N,K]^T, A/B bf16 K-contiguous. bf16 MFMA 16x16x32.
// m97 structure: 128-class tile, BK=64, SINGLE-buffered LDS (32KB),
// 2 barriers per K-step, both operands staged via global_load_lds with
// pre-swizzled global source (linear LDS dest, XOR-swizzled read).
// 4 blocks/CU -> cross-block MFMA/DMA overlap hides the barrier drain.
template<int BM, int BN, int EPI, bool XCD1D>
__global__ __launch_bounds__(256, 4) void gemm_bt(
    const short* __restrict__ A, const short* __restrict__ B, void* __restrict__ Cv,
    const float* __restrict__ bias, const unsigned short* __restrict__ residb,
    float* __restrict__ sumsq,
    long lda, long ldb, long ldc, int K, float escale,
    long aZ, long bZ, long cZ, int biasZ, int ncolb)
{
  constexpr int BK = 64;
  constexpr int WM = BM / 2, WN = BN / 2, MR = WM / 16, NR = WN / 16;
  __shared__ __align__(16) short As[BM * BK];
  __shared__ __align__(16) short Bs[BN * BK];
  const int t = threadIdx.x;
  const int zb = blockIdx.z;
  long bxc, byp;
  if constexpr (XCD1D) {
    int bid = blockIdx.x;
    int per = gridDim.x >> 3;       // blocks per XCD (grid % 8 == 0)
    int ppx = per / ncolb;          // row panels per XCD
    int xcd = bid & 7, j = bid >> 3;
    byp = (long)xcd * ppx + j / ncolb;
    bxc = j % ncolb;
  } else {
    byp = blockIdx.x; bxc = blockIdx.y;
  }
  const long row0 = byp * BM;
  const long col0 = bxc * BN;
  const int wave = t >> 6, lane = t & 63;
  const int wr = wave >> 1, wc = wave & 1;
  const int lr = lane & 15, lg = lane >> 4;
  const short* Az = A + (size_t)zb * aZ;
  const short* Bz = B + (size_t)zb * bZ;
  const int lrow8 = lane >> 3;             // row within 8-row chunk
  const int lgran = (lane & 7) ^ lrow8;    // pre-swizzled source granule

  auto dmaA = [&](int k0) {
    #pragma unroll
    for (int i = 0; i < BM / 32; ++i) {
      int c = wave * (BM / 32) + i;    // 1KB chunk = 8 rows
      gload16(Az + (size_t)(row0 + c * 8 + lrow8) * lda + k0 + lgran * 8,
              &As[c * 512]);
    }
  };
  auto dmaB = [&](int k0) {
    #pragma unroll
    for (int i = 0; i < BN / 32; ++i) {
      int c = wave * (BN / 32) + i;
      gload16(Bz + (size_t)(col0 + c * 8 + lrow8) * ldb + k0 + lgran * 8,
              &Bs[c * 512]);
    }
  };

  const f32x4 zero4 = {0.f, 0.f, 0.f, 0.f};
  f32x4 acc[MR][NR];
  #pragma unroll
  for (int m = 0; m < MR; ++m)
    #pragma unroll
    for (int n = 0; n < NR; ++n) acc[m][n] = zero4;

  dmaA(0); dmaB(0);
  __syncthreads();   // drains DMA (vmcnt0 before barrier)

  const int nk = K / BK;
  for (int kt = 0; kt < nk; ++kt) {
    #pragma unroll
    for (int kk = 0; kk < 2; ++kk) {
      short8 a[MR], b[NR];
      #pragma unroll
      for (int m = 0; m < MR; ++m) {
        int row = wr * WM + m * 16 + lr, col = kk * 32 + lg * 8;
        a[m] = *(const short8*)&As[row * 64 + (col ^ ((row & 7) << 3))];
      }
      #pragma unroll
      for (int n = 0; n < NR; ++n) {
        int row = wc * WN + n * 16 + lr, col = kk * 32 + lg * 8;
        b[n] = *(const short8*)&Bs[row * 64 + (col ^ ((row & 7) << 3))];
      }
      #pragma unroll
      for (int m = 0; m < MR; ++m)
        #pragma unroll
        for (int n = 0; n < NR; ++n)
          acc[m][n] = __builtin_amdgcn_mfma_f32_16x16x32_bf16(a[m], b[n], acc[m][n], 0, 0, 0);
    }
    if (kt + 1 < nk) {
      __syncthreads();                    // all waves done reading tile kt
      dmaA((kt + 1) * BK); dmaB((kt + 1) * BK);
      __syncthreads();                    // DMA drained
    }
  }

  const float* biasz = bias ? (bias + (size_t)zb * biasZ) : nullptr;
  float* Cf = (float*)Cv;
  unsigned short* Cb = (unsigned short*)Cv;
  #pragma unroll
  for (int m = 0; m < MR; ++m) {
    #pragma unroll
    for (int i = 0; i < 4; ++i) {
      long row = row0 + wr * WM + m * 16 + lg * 4 + i;
      float sq = 0.f;
      #pragma unroll
      for (int n = 0; n < NR; ++n) {
        long col = col0 + wc * WN + n * 16 + lr;
        float v = acc[m][n][i];
        if (biasz) v += biasz[col];
        v *= escale;
        size_t ci = (size_t)zb * cZ + (size_t)row * ldc + col;
        if constexpr (EPI == EPI_F32_RESID) {
          v += b2f(residb[(size_t)row * ldc + col]);
          Cf[ci] = v;
        } else if constexpr (EPI == EPI_F32_SUMSQ) {
          Cf[ci] = v;
        } else {
          Cb[ci] = f2bs(v);
        }
        sq += v * v;
      }
      if constexpr (EPI == EPI_F32_SUMSQ || EPI == EPI_BF16_SUMSQ) {
        #pragma unroll
        for (int off = 1; off < 16; off <<= 1) sq += __shfl_xor(sq, off);
        if (lr == 0) atomicAdd(&sumsq[row], sq);
      }
    }
  }
}

__global__ __launch_bounds__(256) void f2b_kernel(const float* __restrict__ s,
                                                  unsigned short* __restrict__ d, long n) {
  long i = (long)blockIdx.x * 256 + threadIdx.x;
  if (i < n) d[i] = f2bs(s[i]);
}

// vectorized f32 -> bf16 (8 elems/thread)
__global__ __launch_bounds__(256) void conv8_kernel(const float* __restrict__ s,
                                                    unsigned short* __restrict__ d, long n8) {
  long i = (long)blockIdx.x * 256 + threadIdx.x;
  if (i < n8) {
    float4 a = ((const float4*)s)[i * 2];
    float4 b = ((const float4*)s)[i * 2 + 1];
    short8 o;
    o[0] = (short)f2bs(a.x); o[1] = (short)f2bs(a.y);
    o[2] = (short)f2bs(a.z); o[3] = (short)f2bs(a.w);
    o[4] = (short)f2bs(b.x); o[5] = (short)f2bs(b.y);
    o[6] = (short)f2bs(b.z); o[7] = (short)f2bs(b.w);
    ((short8*)d)[i] = o;
  }
}

// WkT[h][n][j] = Wk[h*64+j][n],  Wk = in_proj_w rows 768..1535
__global__ __launch_bounds__(256) void wkT_kernel(const float* __restrict__ ipw,
                                                  unsigned short* __restrict__ d) {
  long i = (long)blockIdx.x * 256 + threadIdx.x;
  if (i < 589824) {
    int h = (int)(i / 49152), r = (int)(i % 49152);
    int nn = r >> 6, j = r & 63;
    d[i] = f2bs(ipw[(size_t)(768 + h * 64 + j) * 768 + nn]);
  }
}

__global__ __launch_bounds__(256) void invnorm_kernel(float* s, int n) {
  int i = blockIdx.x * 256 + threadIdx.x;
  if (i < n) s[i] = 1.f / (sqrtf(s[i]) + 1e-6f);
}

// in-place bf16 row scale: xb[row][*] *= invn[row]   (8 elems/thread, row=i/96)
__global__ __launch_bounds__(256) void xqnorm_kernel(unsigned short* __restrict__ xb,
                                                     const float* __restrict__ invn) {
  long i = (long)blockIdx.x * 256 + threadIdx.x;  // 8192*96
  float inv = invn[i / 96];
  short8 v = ((const short8*)xb)[i];
  short8 o;
  #pragma unroll
  for (int j = 0; j < 8; ++j) o[j] = (short)f2bs(b2f((unsigned short)v[j]) * inv);
  ((short8*)xb)[i] = o;
}

// Per-token fused: S = (qk . z)*invn -> softmax_w -> a = attn*invn -> u = a @ z
// QK^T on MFMA (K=768 split over 4 waves), PV vectorized short8 (conflict-free).
// u may alias qk (qk slice fully staged to LDS before write).
__global__ __launch_bounds__(256) void attn_kernel(
    const unsigned short* __restrict__ z, const unsigned short* __restrict__ qk,
    const float* __restrict__ invn, unsigned short* __restrict__ u)
{
  __shared__ __align__(16) unsigned short zl[16 * 768];
  __shared__ __align__(16) unsigned short ql[16 * 768];  // rows 12..15 unused
  __shared__ float sc[3][256];
  __shared__ float al[256];
  __shared__ float il[16];
  const int t = threadIdx.x;
  const long m = blockIdx.x;
  const int wv = t >> 6, lane = t & 63;
  const int lr = lane & 15, lg = lane >> 4;

  // stage (granule-XOR swizzle: 16B granule g stored at g ^ (row&7))
  for (int s = t; s < 1536; s += 256) {
    int row = s / 96, g = s % 96;
    *(short8*)&zl[row * 768 + ((g ^ (row & 7)) << 3)] =
        *(const short8*)(z + m * 12288 + (size_t)s * 8);
  }
  for (int s = t; s < 1152; s += 256) {
    int row = s / 96, g = s % 96;
    *(short8*)&ql[row * 768 + ((g ^ (row & 7)) << 3)] =
        *(const short8*)(qk + m * 9216 + (size_t)s * 8);
  }
  if (t < 16) il[t] = invn[m * 16 + t];
  __syncthreads();

  // QK^T: S[h][w] = sum_k ql[h][k] * zl[w][k]; wave wv covers k in [wv*192, +192)
  f32x4 c = {0.f, 0.f, 0.f, 0.f};
  #pragma unroll
  for (int i = 0; i < 6; ++i) {
    int gb = wv * 24 + i * 4 + lg;   // 16B granule index along K
    short8 a = *(const short8*)&ql[lr * 768 + ((gb ^ (lr & 7)) << 3)];
    short8 b = *(const short8*)&zl[lr * 768 + ((gb ^ (lr & 7)) << 3)];
    c = __builtin_amdgcn_mfma_f32_16x16x32_bf16(a, b, c, 0, 0, 0);
  }
  if (wv > 0) {
    #pragma unroll
    for (int i = 0; i < 4; ++i) sc[wv - 1][(lg * 4 + i) * 16 + lr] = c[i];
  }
  __syncthreads();
  if (wv == 0) {
    // lane holds S[h=lg*4+i][w=lr]; softmax over w (16-lane shfl)
    #pragma unroll
    for (int i = 0; i < 4; ++i) {
      int idx = (lg * 4 + i) * 16 + lr;
      float s = (c[i] + sc[0][idx] + sc[1][idx] + sc[2][idx]) * il[lr];
      float mx = s;
      #pragma unroll
      for (int off = 1; off < 16; off <<= 1) mx = fmaxf(mx, __shfl_xor(mx, off));
      float e = __expf(s - mx);
      float sum = e;
      #pragma unroll
      for (int off = 1; off < 16; off <<= 1) sum += __shfl_xor(sum, off);
      al[idx] = e / sum * il[lr];
    }
  }
  __syncthreads();

  // PV: u[h][d0..d0+8) = sum_w al[h*16+w] * zl[w][d0..]
  for (int s = t; s < 1152; s += 256) {
    int h = s / 96, gd = s % 96;
    float acc[8] = {0.f, 0.f, 0.f, 0.f, 0.f, 0.f, 0.f, 0.f};
    #pragma unroll
    for (int w = 0; w < 16; ++w) {
      float aw = al[h * 16 + w];
      short8 zz = *(const short8*)&zl[w * 768 + ((gd ^ (w & 7)) << 3)];
      #pragma unroll
      for (int j = 0; j < 8; ++j) acc[j] += aw * b2f((unsigned short)zz[j]);
    }
    short8 o;
    #pragma unroll
    for (int j = 0; j < 8; ++j) o[j] = (short)f2bs(acc[j]);
    *(short8*)&u[m * 9216 + (size_t)s * 8] = o;
  }
}

__global__ __launch_bounds__(256) void ln_kernel(const float* __restrict__ R,
                                                 const float* __restrict__ w,
                                                 const float* __restrict__ b,
                                                 float* __restrict__ out) {
  const long row = blockIdx.x;
  const int t = threadIdx.x;
  const float* rr = R + row * 768;
  float v0 = rr[t], v1 = rr[t + 256], v2 = rr[t + 512];
  float s = v0 + v1 + v2;
  #pragma unroll
  for (int off = 1; off < 64; off <<= 1) s += __shfl_xor(s, off);
  __shared__ float ps[4];
  __shared__ float ps2[4];
  const int wave = t >> 6, lane = t & 63;
  if (lane == 0) ps[wave] = s;
  __syncthreads();
  const float mean = (ps[0] + ps[1] + ps[2] + ps[3]) * (1.f / 768.f);
  const float d0 = v0 - mean, d1 = v1 - mean, d2 = v2 - mean;
  float q = d0 * d0 + d1 * d1 + d2 * d2;
  #pragma unroll
  for (int off = 1; off < 64; off <<= 1) q += __shfl_xor(q, off);
  if (lane == 0) ps2[wave] = q;
  __syncthreads();
  const float var = (ps2[0] + ps2[1] + ps2[2] + ps2[3]) * (1.f / 768.f);
  const float rs = rsqrtf(var + 1e-6f);
  float* oo = out + row * 768;
  oo[t]       = d0 * rs * w[t]       + b[t];
  oo[t + 256] = d1 * rs * w[t + 256] + b[t + 256];
  oo[t + 512] = d2 * rs * w[t + 512] + b[t + 512];
}

extern "C" void kernel_launch(void* const* d_in, const int* in_sizes, int n_in,
                              void* d_out, int out_size, void* d_ws, size_t ws_size,
                              hipStream_t stream) {
  const float* x   = (const float*)d_in[0];   // (8,1024,1536)
  const float* y   = (const float*)d_in[1];   // (8,16384,1024)
  const float* Wx  = (const float*)d_in[2];   // (768,1536)
  const float* bx  = (const float*)d_in[3];
  const float* Wy  = (const float*)d_in[4];   // (768,1024)
  const float* by  = (const float*)d_in[5];
  const float* ipw = (const float*)d_in[6];   // (2304,768)
  const float* ipb = (const float*)d_in[7];
  const float* Wo  = (const float*)d_in[8];   // (768,768)
  const float* ob  = (const float*)d_in[9];
  const float* lnw = (const float*)d_in[10];
  const float* lnb = (const float*)d_in[11];
  float* out = (float*)d_out;

  char* ws = (char*)d_ws;
  size_t off = 0;
  auto alloc = [&](size_t bytes) {
    void* p = ws + off;
    off += (bytes + 4095) & ~(size_t)4095;
    return p;
  };
  unsigned short* Wx_b  = (unsigned short*)alloc(768L * 1536 * 2);
  unsigned short* Wy_b  = (unsigned short*)alloc(768L * 1024 * 2);
  unsigned short* Wq_b  = (unsigned short*)alloc(768L * 768 * 2);
  unsigned short* WkT_b = (unsigned short*)alloc(768L * 768 * 2);
  unsigned short* Wv_b  = (unsigned short*)alloc(768L * 768 * 2);
  unsigned short* Wo_b  = (unsigned short*)alloc(768L * 768 * 2);
  float* ssx = (float*)alloc(8192L * 4);        // sumsq -> invnorm (x path)
  float* ssy = (float*)alloc(131072L * 4);      // sumsq -> invnorm (y path)
  unsigned short* z_b  = (unsigned short*)alloc(131072L * 768 * 2);
  unsigned short* xq_b = (unsigned short*)alloc(8192L * 768 * 2);
  // ---- region shared with y_b (y_b dead after z GEMM; these used after) ----
  char* yreg = (char*)alloc(134217728L * 2);    // 256 MB
  unsigned short* y_b  = (unsigned short*)yreg;
  unsigned short* x_b  = (unsigned short*)yreg;                    // 25.2 MB
  unsigned short* q_b  = (unsigned short*)(yreg + 25165824);       // 12.6 MB
  unsigned short* qk_b = (unsigned short*)(yreg + 37748736);       // 151 MB (also u)
  unsigned short* o_b  = (unsigned short*)(yreg + 188743680);      // 12.6 MB
  float*          r_f  = (float*)(yreg + 201326592);               // 25.2 MB
  (void)ws_size; (void)in_sizes; (void)n_in; (void)out_size;

  hipMemsetAsync(ssx, 0, 8192L * 4, stream);
  hipMemsetAsync(ssy, 0, 131072L * 4, stream);

  // weights -> bf16
  f2b_kernel<<<4608, 256, 0, stream>>>(Wx, Wx_b, 768L * 1536);
  f2b_kernel<<<3072, 256, 0, stream>>>(Wy, Wy_b, 768L * 1024);
  f2b_kernel<<<2304, 256, 0, stream>>>(ipw, Wq_b, 589824);               // Wq
  wkT_kernel<<<2304, 256, 0, stream>>>(ipw, WkT_b);                      // Wk^T per head
  f2b_kernel<<<2304, 256, 0, stream>>>(ipw + 2 * 589824, Wv_b, 589824);  // Wv
  f2b_kernel<<<2304, 256, 0, stream>>>(Wo, Wo_b, 589824);

  // y -> bf16 (vectorized), then z = y @ Wy^T + by (+ sumsq), XCD-contiguous
  conv8_kernel<<<65536, 256, 0, stream>>>(y, y_b, 16777216L);
  gemm_bt<128, 128, EPI_BF16_SUMSQ, true><<<6144, 256, 0, stream>>>(
      (const short*)y_b, (const short*)Wy_b, z_b, by, nullptr, ssy,
      1024, 1024, 768, 1024, 1.f, 0, 0, 0, 0, 6);
  invnorm_kernel<<<512, 256, 0, stream>>>(ssy, 131072);

  // x -> bf16, xq = x @ Wx^T + bx (bf16 + sumsq), then scale rows in place
  conv8_kernel<<<6144, 256, 0, stream>>>(x, x_b, 1572864L);
  gemm_bt<128, 128, EPI_BF16_SUMSQ, false><<<dim3(64, 6, 1), 256, 0, stream>>>(
      (const short*)x_b, (const short*)Wx_b, xq_b, bx, nullptr, ssx,
      1536, 1536, 768, 1536, 1.f, 0, 0, 0, 0, 0);
  invnorm_kernel<<<32, 256, 0, stream>>>(ssx, 8192);
  xqnorm_kernel<<<3072, 256, 0, stream>>>(xq_b, ssx);

  // q = xq @ Wq^T + bq
  gemm_bt<128, 128, EPI_BF16, false><<<dim3(64, 6, 1), 256, 0, stream>>>(
      (const short*)xq_b, (const short*)Wq_b, q_b, ipb, nullptr, nullptr,
      768, 768, 768, 768, 1.f, 0, 0, 0, 0, 0);

  // qk[m,h,:] = scale * q[m,h*64:+64] @ WkT[h]   (bk dropped: softmax-invariant)
  gemm_bt<128, 128, EPI_BF16, false><<<dim3(64, 6, 12), 256, 0, stream>>>(
      (const short*)q_b, (const short*)WkT_b, qk_b, nullptr, nullptr, nullptr,
      768, 64, 9216, 64, 0.125f, 64, 49152, 768, 0, 0);

  // fused scores/softmax/u  (u overwrites qk slice per token)
  attn_kernel<<<8192, 256, 0, stream>>>(z_b, qk_b, ssy, qk_b);

  // o[:,h*64:+64] = u[:,h,:] @ Wv_h^T + bv_h
  gemm_bt<128, 64, EPI_BF16, false><<<dim3(64, 1, 12), 256, 0, stream>>>(
      (const short*)qk_b, (const short*)Wv_b, o_b, ipb + 1536, nullptr, nullptr,
      9216, 768, 768, 768, 1.f, 768, 49152, 64, 64, 0);

  // r = o @ out_w^T + out_b + xq (bf16 residual)
  gemm_bt<128, 128, EPI_F32_RESID, false><<<dim3(64, 6, 1), 256, 0, stream>>>(
      (const short*)o_b, (const short*)Wo_b, r_f, ob, xq_b, nullptr,
      768, 768, 768, 768, 1.f, 0, 0, 0, 0, 0);

  ln_kernel<<<8192, 256, 0, stream>>>(r_f, lnw, lnb, out);
}

// Round 7
// 735.780 us; speedup vs baseline: 1.3242x; 1.1758x over previous
//
#include <hip/hip_runtime.h>
#include <hip/hip_bf16.h>

typedef __attribute__((ext_vector_type(8))) short short8;
typedef __attribute__((ext_vector_type(4))) float f32x4;

static __device__ __forceinline__ float b2f(unsigned short u) {
  return __uint_as_float(((unsigned int)u) << 16);
}
static __device__ __forceinline__ unsigned short f2bs(float f) {
  unsigned int u = __float_as_uint(f);
  u = u + 0x7FFFu + ((u >> 16) & 1u);   // RNE (no NaN inputs here)
  return (unsigned short)(u >> 16);
}
// pair f32 -> packed bf16 (HW v_cvt_pk_bf16_f32, RNE)
static __device__ __forceinline__ unsigned int cvt2(float a, float b) {
  __hip_bfloat162 h = __float22bfloat162_rn(make_float2(a, b));
  return *(unsigned int*)&h;
}

// async global->LDS DMA, 16B per lane; LDS dest = wave-uniform base + lane*16
static __device__ __forceinline__ void gload16(const void* g, void* l) {
  __builtin_amdgcn_global_load_lds(
      (const __attribute__((address_space(1))) void*)g,
      (__attribute__((address_space(3))) void*)l, 16, 0, 0);
}

enum { EPI_F32_SUMSQ = 0, EPI_BF16_SUMSQ = 1, EPI_BF16 = 2, EPI_F32_RESID = 3 };

// ---------------- bf16-A GEMM (m97 structure, proven Round 6) ----------------
template<int BM, int BN, int EPI, bool XCD1D>
__global__ __launch_bounds__(256, 4) void gemm_bt(
    const short* __restrict__ A, const short* __restrict__ B, void* __restrict__ Cv,
    const float* __restrict__ bias, const unsigned short* __restrict__ residb,
    float* __restrict__ sumsq,
    long lda, long ldb, long ldc, int K, float escale,
    long aZ, long bZ, long cZ, int biasZ, int ncolb)
{
  constexpr int BK = 64;
  constexpr int WM = BM / 2, WN = BN / 2, MR = WM / 16, NR = WN / 16;
  __shared__ __align__(16) short As[BM * BK];
  __shared__ __align__(16) short Bs[BN * BK];
  const int t = threadIdx.x;
  const int zb = blockIdx.z;
  long bxc, byp;
  if constexpr (XCD1D) {
    int bid = blockIdx.x;
    int per = gridDim.x >> 3;
    int ppx = per / ncolb;
    int xcd = bid & 7, j = bid >> 3;
    byp = (long)xcd * ppx + j / ncolb;
    bxc = j % ncolb;
  } else {
    byp = blockIdx.x; bxc = blockIdx.y;
  }
  const long row0 = byp * BM;
  const long col0 = bxc * BN;
  const int wave = t >> 6, lane = t & 63;
  const int wr = wave >> 1, wc = wave & 1;
  const int lr = lane & 15, lg = lane >> 4;
  const short* Az = A + (size_t)zb * aZ;
  const short* Bz = B + (size_t)zb * bZ;
  const int lrow8 = lane >> 3;
  const int lgran = (lane & 7) ^ lrow8;

  auto dmaA = [&](int k0) {
    #pragma unroll
    for (int i = 0; i < BM / 32; ++i) {
      int c = wave * (BM / 32) + i;
      gload16(Az + (size_t)(row0 + c * 8 + lrow8) * lda + k0 + lgran * 8,
              &As[c * 512]);
    }
  };
  auto dmaB = [&](int k0) {
    #pragma unroll
    for (int i = 0; i < BN / 32; ++i) {
      int c = wave * (BN / 32) + i;
      gload16(Bz + (size_t)(col0 + c * 8 + lrow8) * ldb + k0 + lgran * 8,
              &Bs[c * 512]);
    }
  };

  const f32x4 zero4 = {0.f, 0.f, 0.f, 0.f};
  f32x4 acc[MR][NR];
  #pragma unroll
  for (int m = 0; m < MR; ++m)
    #pragma unroll
    for (int n = 0; n < NR; ++n) acc[m][n] = zero4;

  dmaA(0); dmaB(0);
  __syncthreads();

  const int nk = K / BK;
  for (int kt = 0; kt < nk; ++kt) {
    #pragma unroll
    for (int kk = 0; kk < 2; ++kk) {
      short8 a[MR], b[NR];
      #pragma unroll
      for (int m = 0; m < MR; ++m) {
        int row = wr * WM + m * 16 + lr, col = kk * 32 + lg * 8;
        a[m] = *(const short8*)&As[row * 64 + (col ^ ((row & 7) << 3))];
      }
      #pragma unroll
      for (int n = 0; n < NR; ++n) {
        int row = wc * WN + n * 16 + lr, col = kk * 32 + lg * 8;
        b[n] = *(const short8*)&Bs[row * 64 + (col ^ ((row & 7) << 3))];
      }
      #pragma unroll
      for (int m = 0; m < MR; ++m)
        #pragma unroll
        for (int n = 0; n < NR; ++n)
          acc[m][n] = __builtin_amdgcn_mfma_f32_16x16x32_bf16(a[m], b[n], acc[m][n], 0, 0, 0);
    }
    if (kt + 1 < nk) {
      __syncthreads();
      dmaA((kt + 1) * BK); dmaB((kt + 1) * BK);
      __syncthreads();
    }
  }

  const float* biasz = bias ? (bias + (size_t)zb * biasZ) : nullptr;
  float* Cf = (float*)Cv;
  unsigned short* Cb = (unsigned short*)Cv;
  #pragma unroll
  for (int m = 0; m < MR; ++m) {
    #pragma unroll
    for (int i = 0; i < 4; ++i) {
      long row = row0 + wr * WM + m * 16 + lg * 4 + i;
      float sq = 0.f;
      #pragma unroll
      for (int n = 0; n < NR; ++n) {
        long col = col0 + wc * WN + n * 16 + lr;
        float v = acc[m][n][i];
        if (biasz) v += biasz[col];
        v *= escale;
        size_t ci = (size_t)zb * cZ + (size_t)row * ldc + col;
        if constexpr (EPI == EPI_F32_RESID) {
          v += b2f(residb[(size_t)row * ldc + col]);
          Cf[ci] = v;
        } else if constexpr (EPI == EPI_F32_SUMSQ) {
          Cf[ci] = v;
        } else {
          Cb[ci] = f2bs(v);
        }
        sq += v * v;
      }
      if constexpr (EPI == EPI_F32_SUMSQ || EPI == EPI_BF16_SUMSQ) {
        #pragma unroll
        for (int off = 1; off < 16; off <<= 1) sq += __shfl_xor(sq, off);
        if (lr == 0) atomicAdd(&sumsq[row], sq);
      }
    }
  }
}

// -------- f32-A fused GEMM: C_bf16[M,768] = A_f32[M,K] @ B_bf16[768,K]^T + bias,
// + row sumsq. A staged raw f32 via global_load_lds (32KB), converted to bf16
// on fragment read with HW cvt_pk. Granule-XOR (row&3) involution both sides.
template<bool XCD1D>
__global__ __launch_bounds__(256, 3) void gemm_af32(
    const float* __restrict__ A, const short* __restrict__ B,
    unsigned short* __restrict__ C, const float* __restrict__ bias,
    float* __restrict__ sumsq, int K, int ncolb)
{
  constexpr int BM = 128, BN = 128, BK = 64, WM = 64, WN = 64, MR = 4, NR = 4;
  __shared__ __align__(16) float Asf[BM * BK];
  __shared__ __align__(16) short Bs[BN * BK];
  const int t = threadIdx.x;
  long bxc, byp;
  if constexpr (XCD1D) {
    int bid = blockIdx.x;
    int per = gridDim.x >> 3;
    int ppx = per / ncolb;
    int xcd = bid & 7, j = bid >> 3;
    byp = (long)xcd * ppx + j / ncolb;
    bxc = j % ncolb;
  } else {
    byp = blockIdx.x; bxc = blockIdx.y;
  }
  const long row0 = byp * BM;
  const long col0 = bxc * BN;
  const int wave = t >> 6, lane = t & 63;
  const int wr = wave >> 1, wc = wave & 1;
  const int lr = lane & 15, lg = lane >> 4;
  const int lrow8 = lane >> 3;
  const int lgran8 = (lane & 7) ^ lrow8;   // B-side (bf16) swizzle
  const int lrow4 = lane >> 4;             // A-side f32: 4 rows per 1KB chunk
  const int lgran16 = (lane & 15) ^ lrow4; // 16B granule ^ (row&3)

  auto dmaAf = [&](int k0) {
    #pragma unroll
    for (int i = 0; i < 8; ++i) {
      int c = wave * 8 + i;              // 4-row chunk
      gload16(A + (size_t)(row0 + c * 4 + lrow4) * K + k0 + lgran16 * 4,
              &Asf[c * 256]);
    }
  };
  auto dmaB = [&](int k0) {
    #pragma unroll
    for (int i = 0; i < 4; ++i) {
      int c = wave * 4 + i;              // 8-row chunk
      gload16(B + (size_t)(col0 + c * 8 + lrow8) * K + k0 + lgran8 * 8,
              &Bs[c * 512]);
    }
  };

  const f32x4 zero4 = {0.f, 0.f, 0.f, 0.f};
  f32x4 acc[MR][NR];
  #pragma unroll
  for (int m = 0; m < MR; ++m)
    #pragma unroll
    for (int n = 0; n < NR; ++n) acc[m][n] = zero4;

  dmaAf(0); dmaB(0);
  __syncthreads();

  const int nk = K / BK;
  for (int kt = 0; kt < nk; ++kt) {
    #pragma unroll
    for (int kk = 0; kk < 2; ++kk) {
      short8 a[MR], b[NR];
      #pragma unroll
      for (int m = 0; m < MR; ++m) {
        int row = wr * WM + m * 16 + lr;
        int j0 = kk * 8 + lg * 2;        // f32 16B-granule index (2 per frag)
        float4 lo = *(const float4*)&Asf[row * 64 + ((j0 ^ (row & 3)) << 2)];
        float4 hi = *(const float4*)&Asf[row * 64 + (((j0 + 1) ^ (row & 3)) << 2)];
        union { short8 s; unsigned int u[4]; } U;
        U.u[0] = cvt2(lo.x, lo.y); U.u[1] = cvt2(lo.z, lo.w);
        U.u[2] = cvt2(hi.x, hi.y); U.u[3] = cvt2(hi.z, hi.w);
        a[m] = U.s;
      }
      #pragma unroll
      for (int n = 0; n < NR; ++n) {
        int row = wc * WN + n * 16 + lr, col = kk * 32 + lg * 8;
        b[n] = *(const short8*)&Bs[row * 64 + (col ^ ((row & 7) << 3))];
      }
      #pragma unroll
      for (int m = 0; m < MR; ++m)
        #pragma unroll
        for (int n = 0; n < NR; ++n)
          acc[m][n] = __builtin_amdgcn_mfma_f32_16x16x32_bf16(a[m], b[n], acc[m][n], 0, 0, 0);
    }
    if (kt + 1 < nk) {
      __syncthreads();
      dmaAf((kt + 1) * BK); dmaB((kt + 1) * BK);
      __syncthreads();
    }
  }

  #pragma unroll
  for (int m = 0; m < MR; ++m) {
    #pragma unroll
    for (int i = 0; i < 4; ++i) {
      long row = row0 + wr * WM + m * 16 + lg * 4 + i;
      float sq = 0.f;
      #pragma unroll
      for (int n = 0; n < NR; ++n) {
        long col = col0 + wc * WN + n * 16 + lr;
        float v = acc[m][n][i] + bias[col];
        C[(size_t)row * 768 + col] = f2bs(v);
        sq += v * v;
      }
      #pragma unroll
      for (int off = 1; off < 16; off <<= 1) sq += __shfl_xor(sq, off);
      if (lr == 0) atomicAdd(&sumsq[row], sq);
    }
  }
}

// all weight conversions in one dispatch
__global__ __launch_bounds__(256) void wconv_kernel(
    const float* __restrict__ Wx, const float* __restrict__ Wy,
    const float* __restrict__ ipw, const float* __restrict__ Wo,
    unsigned short* __restrict__ dWx, unsigned short* __restrict__ dWy,
    unsigned short* __restrict__ dWq, unsigned short* __restrict__ dWkT,
    unsigned short* __restrict__ dWv, unsigned short* __restrict__ dWo)
{
  long i = (long)blockIdx.x * 256 + threadIdx.x;
  if (i < 1179648) { dWx[i] = f2bs(Wx[i]); return; }
  i -= 1179648;
  if (i < 786432) { dWy[i] = f2bs(Wy[i]); return; }
  i -= 786432;
  if (i < 589824) { dWq[i] = f2bs(ipw[i]); return; }
  i -= 589824;
  if (i < 589824) {  // WkT[h][n][j] = Wk[h*64+j][n]
    int h = (int)(i / 49152), r = (int)(i % 49152);
    int nn = r >> 6, j = r & 63;
    dWkT[i] = f2bs(ipw[(size_t)(768 + h * 64 + j) * 768 + nn]);
    return;
  }
  i -= 589824;
  if (i < 589824) { dWv[i] = f2bs(ipw[2 * 589824 + i]); return; }
  i -= 589824;
  if (i < 589824) { dWo[i] = f2bs(Wo[i]); }
}

// in-place bf16 row scale by 1/(sqrt(sumsq)+eps)
__global__ __launch_bounds__(256) void xqnorm_kernel(unsigned short* __restrict__ xb,
                                                     const float* __restrict__ ss) {
  long i = (long)blockIdx.x * 256 + threadIdx.x;  // 8192*96
  float inv = 1.f / (sqrtf(ss[i / 96]) + 1e-6f);
  short8 v = ((const short8*)xb)[i];
  short8 o;
  #pragma unroll
  for (int j = 0; j < 8; ++j) o[j] = (short)f2bs(b2f((unsigned short)v[j]) * inv);
  ((short8*)xb)[i] = o;
}

// Per-token fused: S = (qk . z)*invn -> softmax_w -> a = attn*invn -> u = a @ z
__global__ __launch_bounds__(256) void attn_kernel(
    const unsigned short* __restrict__ z, const unsigned short* __restrict__ qk,
    const float* __restrict__ ssy, unsigned short* __restrict__ u)
{
  __shared__ __align__(16) unsigned short zl[16 * 768];
  __shared__ __align__(16) unsigned short ql[16 * 768];
  __shared__ float sc[3][256];
  __shared__ float al[256];
  __shared__ float il[16];
  const int t = threadIdx.x;
  const long m = blockIdx.x;
  const int wv = t >> 6, lane = t & 63;
  const int lr = lane & 15, lg = lane >> 4;

  for (int s = t; s < 1536; s += 256) {
    int row = s / 96, g = s % 96;
    *(short8*)&zl[row * 768 + ((g ^ (row & 7)) << 3)] =
        *(const short8*)(z + m * 12288 + (size_t)s * 8);
  }
  for (int s = t; s < 1152; s += 256) {
    int row = s / 96, g = s % 96;
    *(short8*)&ql[row * 768 + ((g ^ (row & 7)) << 3)] =
        *(const short8*)(qk + m * 9216 + (size_t)s * 8);
  }
  if (t < 16) il[t] = 1.f / (sqrtf(ssy[m * 16 + t]) + 1e-6f);
  __syncthreads();

  f32x4 c = {0.f, 0.f, 0.f, 0.f};
  #pragma unroll
  for (int i = 0; i < 6; ++i) {
    int gb = wv * 24 + i * 4 + lg;
    short8 a = *(const short8*)&ql[lr * 768 + ((gb ^ (lr & 7)) << 3)];
    short8 b = *(const short8*)&zl[lr * 768 + ((gb ^ (lr & 7)) << 3)];
    c = __builtin_amdgcn_mfma_f32_16x16x32_bf16(a, b, c, 0, 0, 0);
  }
  if (wv > 0) {
    #pragma unroll
    for (int i = 0; i < 4; ++i) sc[wv - 1][(lg * 4 + i) * 16 + lr] = c[i];
  }
  __syncthreads();
  if (wv == 0) {
    #pragma unroll
    for (int i = 0; i < 4; ++i) {
      int idx = (lg * 4 + i) * 16 + lr;
      float s = (c[i] + sc[0][idx] + sc[1][idx] + sc[2][idx]) * il[lr];
      float mx = s;
      #pragma unroll
      for (int off = 1; off < 16; off <<= 1) mx = fmaxf(mx, __shfl_xor(mx, off));
      float e = __expf(s - mx);
      float sum = e;
      #pragma unroll
      for (int off = 1; off < 16; off <<= 1) sum += __shfl_xor(sum, off);
      al[idx] = e / sum * il[lr];
    }
  }
  __syncthreads();

  for (int s = t; s < 1152; s += 256) {
    int h = s / 96, gd = s % 96;
    float acc[8] = {0.f, 0.f, 0.f, 0.f, 0.f, 0.f, 0.f, 0.f};
    #pragma unroll
    for (int w = 0; w < 16; ++w) {
      float aw = al[h * 16 + w];
      short8 zz = *(const short8*)&zl[w * 768 + ((gd ^ (w & 7)) << 3)];
      #pragma unroll
      for (int j = 0; j < 8; ++j) acc[j] += aw * b2f((unsigned short)zz[j]);
    }
    short8 o;
    #pragma unroll
    for (int j = 0; j < 8; ++j) o[j] = (short)f2bs(acc[j]);
    *(short8*)&u[m * 9216 + (size_t)s * 8] = o;
  }
}

__global__ __launch_bounds__(256) void ln_kernel(const float* __restrict__ R,
                                                 const float* __restrict__ w,
                                                 const float* __restrict__ b,
                                                 float* __restrict__ out) {
  const long row = blockIdx.x;
  const int t = threadIdx.x;
  const float* rr = R + row * 768;
  float v0 = rr[t], v1 = rr[t + 256], v2 = rr[t + 512];
  float s = v0 + v1 + v2;
  #pragma unroll
  for (int off = 1; off < 64; off <<= 1) s += __shfl_xor(s, off);
  __shared__ float ps[4];
  __shared__ float ps2[4];
  const int wave = t >> 6, lane = t & 63;
  if (lane == 0) ps[wave] = s;
  __syncthreads();
  const float mean = (ps[0] + ps[1] + ps[2] + ps[3]) * (1.f / 768.f);
  const float d0 = v0 - mean, d1 = v1 - mean, d2 = v2 - mean;
  float q = d0 * d0 + d1 * d1 + d2 * d2;
  #pragma unroll
  for (int off = 1; off < 64; off <<= 1) q += __shfl_xor(q, off);
  if (lane == 0) ps2[wave] = q;
  __syncthreads();
  const float var = (ps2[0] + ps2[1] + ps2[2] + ps2[3]) * (1.f / 768.f);
  const float rs = rsqrtf(var + 1e-6f);
  float* oo = out + row * 768;
  oo[t]       = d0 * rs * w[t]       + b[t];
  oo[t + 256] = d1 * rs * w[t + 256] + b[t + 256];
  oo[t + 512] = d2 * rs * w[t + 512] + b[t + 512];
}

extern "C" void kernel_launch(void* const* d_in, const int* in_sizes, int n_in,
                              void* d_out, int out_size, void* d_ws, size_t ws_size,
                              hipStream_t stream) {
  const float* x   = (const float*)d_in[0];   // (8,1024,1536)
  const float* y   = (const float*)d_in[1];   // (8,16384,1024)
  const float* Wx  = (const float*)d_in[2];   // (768,1536)
  const float* bx  = (const float*)d_in[3];
  const float* Wy  = (const float*)d_in[4];   // (768,1024)
  const float* by  = (const float*)d_in[5];
  const float* ipw = (const float*)d_in[6];   // (2304,768)
  const float* ipb = (const float*)d_in[7];
  const float* Wo  = (const float*)d_in[8];   // (768,768)
  const float* ob  = (const float*)d_in[9];
  const float* lnw = (const float*)d_in[10];
  const float* lnb = (const float*)d_in[11];
  float* out = (float*)d_out;

  char* ws = (char*)d_ws;
  size_t off = 0;
  auto alloc = [&](size_t bytes) {
    void* p = ws + off;
    off += (bytes + 4095) & ~(size_t)4095;
    return p;
  };
  unsigned short* Wx_b  = (unsigned short*)alloc(768L * 1536 * 2);
  unsigned short* Wy_b  = (unsigned short*)alloc(768L * 1024 * 2);
  unsigned short* Wq_b  = (unsigned short*)alloc(768L * 768 * 2);
  unsigned short* WkT_b = (unsigned short*)alloc(768L * 768 * 2);
  unsigned short* Wv_b  = (unsigned short*)alloc(768L * 768 * 2);
  unsigned short* Wo_b  = (unsigned short*)alloc(768L * 768 * 2);
  float* ssx = (float*)alloc(8192L * 4);
  float* ssy = (float*)alloc(131072L * 4);
  unsigned short* z_b  = (unsigned short*)alloc(131072L * 768 * 2);
  unsigned short* xq_b = (unsigned short*)alloc(8192L * 768 * 2);
  char* reg = (char*)alloc(134217728L * 2);    // 256 MB scratch region
  unsigned short* q_b  = (unsigned short*)(reg + 25165824);       // 12.6 MB
  unsigned short* qk_b = (unsigned short*)(reg + 37748736);       // 151 MB (also u)
  unsigned short* o_b  = (unsigned short*)(reg + 188743680);      // 12.6 MB
  float*          r_f  = (float*)(reg + 201326592);               // 25.2 MB
  (void)ws_size; (void)in_sizes; (void)n_in; (void)out_size;

  hipMemsetAsync(ssx, 0, 8192L * 4, stream);
  hipMemsetAsync(ssy, 0, 131072L * 4, stream);

  // all weights -> bf16 in one dispatch (4325376 elems)
  wconv_kernel<<<16896, 256, 0, stream>>>(Wx, Wy, ipw, Wo,
                                          Wx_b, Wy_b, Wq_b, WkT_b, Wv_b, Wo_b);

  // z = y @ Wy^T + by (bf16 + sumsq), f32 A fused, XCD-contiguous panels
  gemm_af32<true><<<6144, 256, 0, stream>>>(
      y, (const short*)Wy_b, z_b, by, ssy, 1024, 6);

  // xq = x @ Wx^T + bx (bf16 + sumsq), then scale rows in place
  gemm_af32<false><<<dim3(64, 6, 1), 256, 0, stream>>>(
      x, (const short*)Wx_b, xq_b, bx, ssx, 1536, 0);
  xqnorm_kernel<<<3072, 256, 0, stream>>>(xq_b, ssx);

  // q = xq @ Wq^T + bq
  gemm_bt<128, 128, EPI_BF16, false><<<dim3(64, 6, 1), 256, 0, stream>>>(
      (const short*)xq_b, (const short*)Wq_b, q_b, ipb, nullptr, nullptr,
      768, 768, 768, 768, 1.f, 0, 0, 0, 0, 0);

  // qk[m,h,:] = scale * q[m,h*64:+64] @ WkT[h]   (bk dropped: softmax-invariant)
  gemm_bt<128, 128, EPI_BF16, false><<<dim3(64, 6, 12), 256, 0, stream>>>(
      (const short*)q_b, (const short*)WkT_b, qk_b, nullptr, nullptr, nullptr,
      768, 64, 9216, 64, 0.125f, 64, 49152, 768, 0, 0);

  // fused scores/softmax/u  (u overwrites qk slice per token)
  attn_kernel<<<8192, 256, 0, stream>>>(z_b, qk_b, ssy, qk_b);

  // o[:,h*64:+64] = u[:,h,:] @ Wv_h^T + bv_h
  gemm_bt<128, 64, EPI_BF16, false><<<dim3(64, 1, 12), 256, 0, stream>>>(
      (const short*)qk_b, (const short*)Wv_b, o_b, ipb + 1536, nullptr, nullptr,
      9216, 768, 768, 768, 1.f, 768, 49152, 64, 64, 0);

  // r = o @ out_w^T + out_b + xq (bf16 residual)
  gemm_bt<128, 128, EPI_F32_RESID, false><<<dim3(64, 6, 1), 256, 0, stream>>>(
      (const short*)o_b, (const short*)Wo_b, r_f, ob, xq_b, nullptr,
      768, 768, 768, 768, 1.f, 0, 0, 0, 0, 0);

  ln_kernel<<<8192, 256, 0, stream>>>(r_f, lnw, lnb, out);
}

// Round 8
// 709.834 us; speedup vs baseline: 1.3726x; 1.0366x over previous
//
#include <hip/hip_runtime.h>
#include <hip/hip_bf16.h>

typedef __attribute__((ext_vector_type(8))) short short8;
typedef __attribute__((ext_vector_type(4))) float f32x4;

static __device__ __forceinline__ float b2f(unsigned short u) {
  return __uint_as_float(((unsigned int)u) << 16);
}
static __device__ __forceinline__ unsigned short f2bs(float f) {
  unsigned int u = __float_as_uint(f);
  u = u + 0x7FFFu + ((u >> 16) & 1u);   // RNE (no NaN inputs here)
  return (unsigned short)(u >> 16);
}
// pair f32 -> packed bf16 (HW v_cvt_pk_bf16_f32, RNE)
static __device__ __forceinline__ unsigned int cvt2(float a, float b) {
  __hip_bfloat162 h = __float22bfloat162_rn(make_float2(a, b));
  return *(unsigned int*)&h;
}

// async global->LDS DMA, 16B per lane; LDS dest = wave-uniform base + lane*16
static __device__ __forceinline__ void gload16(const void* g, void* l) {
  __builtin_amdgcn_global_load_lds(
      (const __attribute__((address_space(1))) void*)g,
      (__attribute__((address_space(3))) void*)l, 16, 0, 0);
}

enum { EPI_F32_SUMSQ = 0, EPI_BF16_SUMSQ = 1, EPI_BF16 = 2, EPI_F32_RESID = 3 };

// ---------------- bf16-A GEMM (m97 structure, proven Round 6) ----------------
template<int BM, int BN, int EPI, bool XCD1D>
__global__ __launch_bounds__(256, 4) void gemm_bt(
    const short* __restrict__ A, const short* __restrict__ B, void* __restrict__ Cv,
    const float* __restrict__ bias, const unsigned short* __restrict__ residb,
    float* __restrict__ sumsq,
    long lda, long ldb, long ldc, int K, float escale,
    long aZ, long bZ, long cZ, int biasZ, int ncolb)
{
  constexpr int BK = 64;
  constexpr int WM = BM / 2, WN = BN / 2, MR = WM / 16, NR = WN / 16;
  __shared__ __align__(16) short As[BM * BK];
  __shared__ __align__(16) short Bs[BN * BK];
  const int t = threadIdx.x;
  const int zb = blockIdx.z;
  long bxc, byp;
  if constexpr (XCD1D) {
    int bid = blockIdx.x;
    int per = gridDim.x >> 3;
    int ppx = per / ncolb;
    int xcd = bid & 7, j = bid >> 3;
    byp = (long)xcd * ppx + j / ncolb;
    bxc = j % ncolb;
  } else {
    byp = blockIdx.x; bxc = blockIdx.y;
  }
  const long row0 = byp * BM;
  const long col0 = bxc * BN;
  const int wave = t >> 6, lane = t & 63;
  const int wr = wave >> 1, wc = wave & 1;
  const int lr = lane & 15, lg = lane >> 4;
  const short* Az = A + (size_t)zb * aZ;
  const short* Bz = B + (size_t)zb * bZ;
  const int lrow8 = lane >> 3;
  const int lgran = (lane & 7) ^ lrow8;

  auto dmaA = [&](int k0) {
    #pragma unroll
    for (int i = 0; i < BM / 32; ++i) {
      int c = wave * (BM / 32) + i;
      gload16(Az + (size_t)(row0 + c * 8 + lrow8) * lda + k0 + lgran * 8,
              &As[c * 512]);
    }
  };
  auto dmaB = [&](int k0) {
    #pragma unroll
    for (int i = 0; i < BN / 32; ++i) {
      int c = wave * (BN / 32) + i;
      gload16(Bz + (size_t)(col0 + c * 8 + lrow8) * ldb + k0 + lgran * 8,
              &Bs[c * 512]);
    }
  };

  const f32x4 zero4 = {0.f, 0.f, 0.f, 0.f};
  f32x4 acc[MR][NR];
  #pragma unroll
  for (int m = 0; m < MR; ++m)
    #pragma unroll
    for (int n = 0; n < NR; ++n) acc[m][n] = zero4;

  dmaA(0); dmaB(0);
  __syncthreads();

  const int nk = K / BK;
  for (int kt = 0; kt < nk; ++kt) {
    #pragma unroll
    for (int kk = 0; kk < 2; ++kk) {
      short8 a[MR], b[NR];
      #pragma unroll
      for (int m = 0; m < MR; ++m) {
        int row = wr * WM + m * 16 + lr, col = kk * 32 + lg * 8;
        a[m] = *(const short8*)&As[row * 64 + (col ^ ((row & 7) << 3))];
      }
      #pragma unroll
      for (int n = 0; n < NR; ++n) {
        int row = wc * WN + n * 16 + lr, col = kk * 32 + lg * 8;
        b[n] = *(const short8*)&Bs[row * 64 + (col ^ ((row & 7) << 3))];
      }
      #pragma unroll
      for (int m = 0; m < MR; ++m)
        #pragma unroll
        for (int n = 0; n < NR; ++n)
          acc[m][n] = __builtin_amdgcn_mfma_f32_16x16x32_bf16(a[m], b[n], acc[m][n], 0, 0, 0);
    }
    if (kt + 1 < nk) {
      __syncthreads();
      dmaA((kt + 1) * BK); dmaB((kt + 1) * BK);
      __syncthreads();
    }
  }

  const float* biasz = bias ? (bias + (size_t)zb * biasZ) : nullptr;
  float* Cf = (float*)Cv;
  unsigned short* Cb = (unsigned short*)Cv;
  #pragma unroll
  for (int m = 0; m < MR; ++m) {
    #pragma unroll
    for (int i = 0; i < 4; ++i) {
      long row = row0 + wr * WM + m * 16 + lg * 4 + i;
      float sq = 0.f;
      #pragma unroll
      for (int n = 0; n < NR; ++n) {
        long col = col0 + wc * WN + n * 16 + lr;
        float v = acc[m][n][i];
        if (biasz) v += biasz[col];
        v *= escale;
        size_t ci = (size_t)zb * cZ + (size_t)row * ldc + col;
        if constexpr (EPI == EPI_F32_RESID) {
          v += b2f(residb[(size_t)row * ldc + col]);
          Cf[ci] = v;
        } else if constexpr (EPI == EPI_F32_SUMSQ) {
          Cf[ci] = v;
        } else {
          Cb[ci] = f2bs(v);
        }
        sq += v * v;
      }
      if constexpr (EPI == EPI_F32_SUMSQ || EPI == EPI_BF16_SUMSQ) {
        #pragma unroll
        for (int off = 1; off < 16; off <<= 1) sq += __shfl_xor(sq, off);
        if (lr == 0) atomicAdd(&sumsq[row], sq);
      }
    }
  }
}

// -------- f32-A fused GEMM: C_bf16[M,768] = A_f32[M,K] @ B_bf16[768,K]^T + bias,
// + row sumsq. A staged raw f32 via global_load_lds (32KB), converted to bf16
// on fragment read with HW cvt_pk. Full-rank granule involution: granule g of
// row r lives at slot g ^ (r&15)  (16 granules/row -> 16 distinct slots across
// a fragment's 16 rows -> conflict-free b128 reads).
template<bool XCD1D>
__global__ __launch_bounds__(256, 3) void gemm_af32(
    const float* __restrict__ A, const short* __restrict__ B,
    unsigned short* __restrict__ C, const float* __restrict__ bias,
    float* __restrict__ sumsq, int K, int ncolb)
{
  constexpr int BM = 128, BN = 128, BK = 64, WM = 64, WN = 64, MR = 4, NR = 4;
  __shared__ __align__(16) float Asf[BM * BK];
  __shared__ __align__(16) short Bs[BN * BK];
  const int t = threadIdx.x;
  long bxc, byp;
  if constexpr (XCD1D) {
    int bid = blockIdx.x;
    int per = gridDim.x >> 3;
    int ppx = per / ncolb;
    int xcd = bid & 7, j = bid >> 3;
    byp = (long)xcd * ppx + j / ncolb;
    bxc = j % ncolb;
  } else {
    byp = blockIdx.x; bxc = blockIdx.y;
  }
  const long row0 = byp * BM;
  const long col0 = bxc * BN;
  const int wave = t >> 6, lane = t & 63;
  const int wr = wave >> 1, wc = wave & 1;
  const int lr = lane & 15, lg = lane >> 4;
  const int lrow8 = lane >> 3;
  const int lgran8 = (lane & 7) ^ lrow8;   // B-side (bf16) swizzle
  const int lrow4 = lane >> 4;             // A-side f32: 4 rows per 1KB chunk

  auto dmaAf = [&](int k0) {
    #pragma unroll
    for (int i = 0; i < 8; ++i) {
      int c = wave * 8 + i;              // 4-row chunk; row = c*4 + lrow4
      // source granule = (lane&15) ^ (row & 15); wave*32 == 0 (mod 16)
      int lg16 = (lane & 15) ^ lrow4 ^ ((i & 3) << 2);
      gload16(A + (size_t)(row0 + c * 4 + lrow4) * K + k0 + lg16 * 4,
              &Asf[c * 256]);
    }
  };
  auto dmaB = [&](int k0) {
    #pragma unroll
    for (int i = 0; i < 4; ++i) {
      int c = wave * 4 + i;              // 8-row chunk
      gload16(B + (size_t)(col0 + c * 8 + lrow8) * K + k0 + lgran8 * 8,
              &Bs[c * 512]);
    }
  };

  const f32x4 zero4 = {0.f, 0.f, 0.f, 0.f};
  f32x4 acc[MR][NR];
  #pragma unroll
  for (int m = 0; m < MR; ++m)
    #pragma unroll
    for (int n = 0; n < NR; ++n) acc[m][n] = zero4;

  dmaAf(0); dmaB(0);
  __syncthreads();

  const int nk = K / BK;
  for (int kt = 0; kt < nk; ++kt) {
    #pragma unroll
    for (int kk = 0; kk < 2; ++kk) {
      short8 a[MR], b[NR];
      #pragma unroll
      for (int m = 0; m < MR; ++m) {
        int row = wr * WM + m * 16 + lr;   // row & 15 == lr
        int j0 = kk * 8 + lg * 2;          // f32 16B-granule index (2 per frag)
        float4 lo = *(const float4*)&Asf[row * 64 + ((j0 ^ lr) << 2)];
        float4 hi = *(const float4*)&Asf[row * 64 + (((j0 + 1) ^ lr) << 2)];
        union { short8 s; unsigned int u[4]; } U;
        U.u[0] = cvt2(lo.x, lo.y); U.u[1] = cvt2(lo.z, lo.w);
        U.u[2] = cvt2(hi.x, hi.y); U.u[3] = cvt2(hi.z, hi.w);
        a[m] = U.s;
      }
      #pragma unroll
      for (int n = 0; n < NR; ++n) {
        int row = wc * WN + n * 16 + lr, col = kk * 32 + lg * 8;
        b[n] = *(const short8*)&Bs[row * 64 + (col ^ ((row & 7) << 3))];
      }
      #pragma unroll
      for (int m = 0; m < MR; ++m)
        #pragma unroll
        for (int n = 0; n < NR; ++n)
          acc[m][n] = __builtin_amdgcn_mfma_f32_16x16x32_bf16(a[m], b[n], acc[m][n], 0, 0, 0);
    }
    if (kt + 1 < nk) {
      __syncthreads();
      dmaAf((kt + 1) * BK); dmaB((kt + 1) * BK);
      __syncthreads();
    }
  }

  #pragma unroll
  for (int m = 0; m < MR; ++m) {
    #pragma unroll
    for (int i = 0; i < 4; ++i) {
      long row = row0 + wr * WM + m * 16 + lg * 4 + i;
      float sq = 0.f;
      #pragma unroll
      for (int n = 0; n < NR; ++n) {
        long col = col0 + wc * WN + n * 16 + lr;
        float v = acc[m][n][i] + bias[col];
        C[(size_t)row * 768 + col] = f2bs(v);
        sq += v * v;
      }
      #pragma unroll
      for (int off = 1; off < 16; off <<= 1) sq += __shfl_xor(sq, off);
      if (lr == 0) atomicAdd(&sumsq[row], sq);
    }
  }
}

// all weight conversions in one dispatch
__global__ __launch_bounds__(256) void wconv_kernel(
    const float* __restrict__ Wx, const float* __restrict__ Wy,
    const float* __restrict__ ipw, const float* __restrict__ Wo,
    unsigned short* __restrict__ dWx, unsigned short* __restrict__ dWy,
    unsigned short* __restrict__ dWq, unsigned short* __restrict__ dWkT,
    unsigned short* __restrict__ dWv, unsigned short* __restrict__ dWo)
{
  long i = (long)blockIdx.x * 256 + threadIdx.x;
  if (i < 1179648) { dWx[i] = f2bs(Wx[i]); return; }
  i -= 1179648;
  if (i < 786432) { dWy[i] = f2bs(Wy[i]); return; }
  i -= 786432;
  if (i < 589824) { dWq[i] = f2bs(ipw[i]); return; }
  i -= 589824;
  if (i < 589824) {  // WkT[h][n][j] = Wk[h*64+j][n]
    int h = (int)(i / 49152), r = (int)(i % 49152);
    int nn = r >> 6, j = r & 63;
    dWkT[i] = f2bs(ipw[(size_t)(768 + h * 64 + j) * 768 + nn]);
    return;
  }
  i -= 589824;
  if (i < 589824) { dWv[i] = f2bs(ipw[2 * 589824 + i]); return; }
  i -= 589824;
  if (i < 589824) { dWo[i] = f2bs(Wo[i]); }
}

// in-place bf16 row scale by 1/(sqrt(sumsq)+eps)
__global__ __launch_bounds__(256) void xqnorm_kernel(unsigned short* __restrict__ xb,
                                                     const float* __restrict__ ss) {
  long i = (long)blockIdx.x * 256 + threadIdx.x;  // 8192*96
  float inv = 1.f / (sqrtf(ss[i / 96]) + 1e-6f);
  short8 v = ((const short8*)xb)[i];
  short8 o;
  #pragma unroll
  for (int j = 0; j < 8; ++j) o[j] = (short)f2bs(b2f((unsigned short)v[j]) * inv);
  ((short8*)xb)[i] = o;
}

// Per-token fused: S = (qk . z)*invn -> softmax_w -> a = attn*invn -> u = a @ z
__global__ __launch_bounds__(256) void attn_kernel(
    const unsigned short* __restrict__ z, const unsigned short* __restrict__ qk,
    const float* __restrict__ ssy, unsigned short* __restrict__ u)
{
  __shared__ __align__(16) unsigned short zl[16 * 768];
  __shared__ __align__(16) unsigned short ql[16 * 768];
  __shared__ float sc[3][256];
  __shared__ float al[256];
  __shared__ float il[16];
  const int t = threadIdx.x;
  const long m = blockIdx.x;
  const int wv = t >> 6, lane = t & 63;
  const int lr = lane & 15, lg = lane >> 4;

  for (int s = t; s < 1536; s += 256) {
    int row = s / 96, g = s % 96;
    *(short8*)&zl[row * 768 + ((g ^ (row & 7)) << 3)] =
        *(const short8*)(z + m * 12288 + (size_t)s * 8);
  }
  for (int s = t; s < 1152; s += 256) {
    int row = s / 96, g = s % 96;
    *(short8*)&ql[row * 768 + ((g ^ (row & 7)) << 3)] =
        *(const short8*)(qk + m * 9216 + (size_t)s * 8);
  }
  if (t < 16) il[t] = 1.f / (sqrtf(ssy[m * 16 + t]) + 1e-6f);
  __syncthreads();

  f32x4 c = {0.f, 0.f, 0.f, 0.f};
  #pragma unroll
  for (int i = 0; i < 6; ++i) {
    int gb = wv * 24 + i * 4 + lg;
    short8 a = *(const short8*)&ql[lr * 768 + ((gb ^ (lr & 7)) << 3)];
    short8 b = *(const short8*)&zl[lr * 768 + ((gb ^ (lr & 7)) << 3)];
    c = __builtin_amdgcn_mfma_f32_16x16x32_bf16(a, b, c, 0, 0, 0);
  }
  if (wv > 0) {
    #pragma unroll
    for (int i = 0; i < 4; ++i) sc[wv - 1][(lg * 4 + i) * 16 + lr] = c[i];
  }
  __syncthreads();
  if (wv == 0) {
    #pragma unroll
    for (int i = 0; i < 4; ++i) {
      int idx = (lg * 4 + i) * 16 + lr;
      float s = (c[i] + sc[0][idx] + sc[1][idx] + sc[2][idx]) * il[lr];
      float mx = s;
      #pragma unroll
      for (int off = 1; off < 16; off <<= 1) mx = fmaxf(mx, __shfl_xor(mx, off));
      float e = __expf(s - mx);
      float sum = e;
      #pragma unroll
      for (int off = 1; off < 16; off <<= 1) sum += __shfl_xor(sum, off);
      al[idx] = e / sum * il[lr];
    }
  }
  __syncthreads();

  for (int s = t; s < 1152; s += 256) {
    int h = s / 96, gd = s % 96;
    float acc[8] = {0.f, 0.f, 0.f, 0.f, 0.f, 0.f, 0.f, 0.f};
    #pragma unroll
    for (int w = 0; w < 16; ++w) {
      float aw = al[h * 16 + w];
      short8 zz = *(const short8*)&zl[w * 768 + ((gd ^ (w & 7)) << 3)];
      #pragma unroll
      for (int j = 0; j < 8; ++j) acc[j] += aw * b2f((unsigned short)zz[j]);
    }
    short8 o;
    #pragma unroll
    for (int j = 0; j < 8; ++j) o[j] = (short)f2bs(acc[j]);
    *(short8*)&u[m * 9216 + (size_t)s * 8] = o;
  }
}

__global__ __launch_bounds__(256) void ln_kernel(const float* __restrict__ R,
                                                 const float* __restrict__ w,
                                                 const float* __restrict__ b,
                                                 float* __restrict__ out) {
  const long row = blockIdx.x;
  const int t = threadIdx.x;
  const float* rr = R + row * 768;
  float v0 = rr[t], v1 = rr[t + 256], v2 = rr[t + 512];
  float s = v0 + v1 + v2;
  #pragma unroll
  for (int off = 1; off < 64; off <<= 1) s += __shfl_xor(s, off);
  __shared__ float ps[4];
  __shared__ float ps2[4];
  const int wave = t >> 6, lane = t & 63;
  if (lane == 0) ps[wave] = s;
  __syncthreads();
  const float mean = (ps[0] + ps[1] + ps[2] + ps[3]) * (1.f / 768.f);
  const float d0 = v0 - mean, d1 = v1 - mean, d2 = v2 - mean;
  float q = d0 * d0 + d1 * d1 + d2 * d2;
  #pragma unroll
  for (int off = 1; off < 64; off <<= 1) q += __shfl_xor(q, off);
  if (lane == 0) ps2[wave] = q;
  __syncthreads();
  const float var = (ps2[0] + ps2[1] + ps2[2] + ps2[3]) * (1.f / 768.f);
  const float rs = rsqrtf(var + 1e-6f);
  float* oo = out + row * 768;
  oo[t]       = d0 * rs * w[t]       + b[t];
  oo[t + 256] = d1 * rs * w[t + 256] + b[t + 256];
  oo[t + 512] = d2 * rs * w[t + 512] + b[t + 512];
}

extern "C" void kernel_launch(void* const* d_in, const int* in_sizes, int n_in,
                              void* d_out, int out_size, void* d_ws, size_t ws_size,
                              hipStream_t stream) {
  const float* x   = (const float*)d_in[0];   // (8,1024,1536)
  const float* y   = (const float*)d_in[1];   // (8,16384,1024)
  const float* Wx  = (const float*)d_in[2];   // (768,1536)
  const float* bx  = (const float*)d_in[3];
  const float* Wy  = (const float*)d_in[4];   // (768,1024)
  const float* by  = (const float*)d_in[5];
  const float* ipw = (const float*)d_in[6];   // (2304,768)
  const float* ipb = (const float*)d_in[7];
  const float* Wo  = (const float*)d_in[8];   // (768,768)
  const float* ob  = (const float*)d_in[9];
  const float* lnw = (const float*)d_in[10];
  const float* lnb = (const float*)d_in[11];
  float* out = (float*)d_out;

  char* ws = (char*)d_ws;
  size_t off = 0;
  auto alloc = [&](size_t bytes) {
    void* p = ws + off;
    off += (bytes + 4095) & ~(size_t)4095;
    return p;
  };
  unsigned short* Wx_b  = (unsigned short*)alloc(768L * 1536 * 2);
  unsigned short* Wy_b  = (unsigned short*)alloc(768L * 1024 * 2);
  unsigned short* Wq_b  = (unsigned short*)alloc(768L * 768 * 2);
  unsigned short* WkT_b = (unsigned short*)alloc(768L * 768 * 2);
  unsigned short* Wv_b  = (unsigned short*)alloc(768L * 768 * 2);
  unsigned short* Wo_b  = (unsigned short*)alloc(768L * 768 * 2);
  float* ssx = (float*)alloc(8192L * 4);
  float* ssy = (float*)alloc(131072L * 4);
  unsigned short* z_b  = (unsigned short*)alloc(131072L * 768 * 2);
  unsigned short* xq_b = (unsigned short*)alloc(8192L * 768 * 2);
  char* reg = (char*)alloc(134217728L * 2);    // 256 MB scratch region
  unsigned short* q_b  = (unsigned short*)(reg + 25165824);       // 12.6 MB
  unsigned short* qk_b = (unsigned short*)(reg + 37748736);       // 151 MB (also u)
  unsigned short* o_b  = (unsigned short*)(reg + 188743680);      // 12.6 MB
  float*          r_f  = (float*)(reg + 201326592);               // 25.2 MB
  (void)ws_size; (void)in_sizes; (void)n_in; (void)out_size;

  hipMemsetAsync(ssx, 0, 8192L * 4, stream);
  hipMemsetAsync(ssy, 0, 131072L * 4, stream);

  // all weights -> bf16 in one dispatch (4325376 elems)
  wconv_kernel<<<16896, 256, 0, stream>>>(Wx, Wy, ipw, Wo,
                                          Wx_b, Wy_b, Wq_b, WkT_b, Wv_b, Wo_b);

  // z = y @ Wy^T + by (bf16 + sumsq), f32 A fused, XCD-contiguous panels
  gemm_af32<true><<<6144, 256, 0, stream>>>(
      y, (const short*)Wy_b, z_b, by, ssy, 1024, 6);

  // xq = x @ Wx^T + bx (bf16 + sumsq), then scale rows in place
  gemm_af32<false><<<dim3(64, 6, 1), 256, 0, stream>>>(
      x, (const short*)Wx_b, xq_b, bx, ssx, 1536, 0);
  xqnorm_kernel<<<3072, 256, 0, stream>>>(xq_b, ssx);

  // q = xq @ Wq^T + bq
  gemm_bt<128, 128, EPI_BF16, false><<<dim3(64, 6, 1), 256, 0, stream>>>(
      (const short*)xq_b, (const short*)Wq_b, q_b, ipb, nullptr, nullptr,
      768, 768, 768, 768, 1.f, 0, 0, 0, 0, 0);

  // qk[m,h,:] = scale * q[m,h*64:+64] @ WkT[h]   (bk dropped: softmax-invariant)
  gemm_bt<128, 128, EPI_BF16, false><<<dim3(64, 6, 12), 256, 0, stream>>>(
      (const short*)q_b, (const short*)WkT_b, qk_b, nullptr, nullptr, nullptr,
      768, 64, 9216, 64, 0.125f, 64, 49152, 768, 0, 0);

  // fused scores/softmax/u  (u overwrites qk slice per token)
  attn_kernel<<<8192, 256, 0, stream>>>(z_b, qk_b, ssy, qk_b);

  // o[:,h*64:+64] = u[:,h,:] @ Wv_h^T + bv_h
  gemm_bt<128, 64, EPI_BF16, false><<<dim3(64, 1, 12), 256, 0, stream>>>(
      (const short*)qk_b, (const short*)Wv_b, o_b, ipb + 1536, nullptr, nullptr,
      9216, 768, 768, 768, 1.f, 768, 49152, 64, 64, 0);

  // r = o @ out_w^T + out_b + xq (bf16 residual)
  gemm_bt<128, 128, EPI_F32_RESID, false><<<dim3(64, 6, 1), 256, 0, stream>>>(
      (const short*)o_b, (const short*)Wo_b, r_f, ob, xq_b, nullptr,
      768, 768, 768, 768, 1.f, 0, 0, 0, 0, 0);

  ln_kernel<<<8192, 256, 0, stream>>>(r_f, lnw, lnb, out);
}

// Round 9
// 692.896 us; speedup vs baseline: 1.4061x; 1.0244x over previous
//
#include <hip/hip_runtime.h>
#include <hip/hip_bf16.h>

typedef __attribute__((ext_vector_type(8))) short short8;
typedef __attribute__((ext_vector_type(4))) float f32x4;

static __device__ __forceinline__ float b2f(unsigned short u) {
  return __uint_as_float(((unsigned int)u) << 16);
}
static __device__ __forceinline__ unsigned short f2bs(float f) {
  unsigned int u = __float_as_uint(f);
  u = u + 0x7FFFu + ((u >> 16) & 1u);   // RNE (no NaN inputs here)
  return (unsigned short)(u >> 16);
}
// pair f32 -> packed bf16 (HW v_cvt_pk_bf16_f32, RNE)
static __device__ __forceinline__ unsigned int cvt2(float a, float b) {
  __hip_bfloat162 h = __float22bfloat162_rn(make_float2(a, b));
  return *(unsigned int*)&h;
}

// async global->LDS DMA, 16B per lane; LDS dest = wave-uniform base + lane*16
static __device__ __forceinline__ void gload16(const void* g, void* l) {
  __builtin_amdgcn_global_load_lds(
      (const __attribute__((address_space(1))) void*)g,
      (__attribute__((address_space(3))) void*)l, 16, 0, 0);
}

enum { EPI_BF16_SUMSQ = 1, EPI_BF16 = 2, EPI_F32_RESID = 3 };

// ---------------- bf16-A GEMM (m97 structure, proven Round 6) ----------------
// rowscale (raw sumsq): EPI_BF16 -> v = acc*escale*rs + bias;
//                       EPI_F32_RESID -> v = acc + bias + rs*resid.
template<int BM, int BN, int EPI, bool XCD1D>
__global__ __launch_bounds__(256, 4) void gemm_bt(
    const short* __restrict__ A, const short* __restrict__ B, void* __restrict__ Cv,
    const float* __restrict__ bias, const unsigned short* __restrict__ residb,
    float* __restrict__ sumsq, const float* __restrict__ rowscale,
    long lda, long ldb, long ldc, int K, float escale,
    long aZ, long bZ, long cZ, int biasZ, int ncolb)
{
  constexpr int BK = 64;
  constexpr int WM = BM / 2, WN = BN / 2, MR = WM / 16, NR = WN / 16;
  __shared__ __align__(16) short As[BM * BK];
  __shared__ __align__(16) short Bs[BN * BK];
  const int t = threadIdx.x;
  const int zb = blockIdx.z;
  long bxc, byp;
  if constexpr (XCD1D) {
    int bid = blockIdx.x;
    int per = gridDim.x >> 3;
    int ppx = per / ncolb;
    int xcd = bid & 7, j = bid >> 3;
    byp = (long)xcd * ppx + j / ncolb;
    bxc = j % ncolb;
  } else {
    byp = blockIdx.x; bxc = blockIdx.y;
  }
  const long row0 = byp * BM;
  const long col0 = bxc * BN;
  const int wave = t >> 6, lane = t & 63;
  const int wr = wave >> 1, wc = wave & 1;
  const int lr = lane & 15, lg = lane >> 4;
  const short* Az = A + (size_t)zb * aZ;
  const short* Bz = B + (size_t)zb * bZ;
  const int lrow8 = lane >> 3;
  const int lgran = (lane & 7) ^ lrow8;

  auto dmaA = [&](int k0) {
    #pragma unroll
    for (int i = 0; i < BM / 32; ++i) {
      int c = wave * (BM / 32) + i;
      gload16(Az + (size_t)(row0 + c * 8 + lrow8) * lda + k0 + lgran * 8,
              &As[c * 512]);
    }
  };
  auto dmaB = [&](int k0) {
    #pragma unroll
    for (int i = 0; i < BN / 32; ++i) {
      int c = wave * (BN / 32) + i;
      gload16(Bz + (size_t)(col0 + c * 8 + lrow8) * ldb + k0 + lgran * 8,
              &Bs[c * 512]);
    }
  };

  const f32x4 zero4 = {0.f, 0.f, 0.f, 0.f};
  f32x4 acc[MR][NR];
  #pragma unroll
  for (int m = 0; m < MR; ++m)
    #pragma unroll
    for (int n = 0; n < NR; ++n) acc[m][n] = zero4;

  dmaA(0); dmaB(0);
  __syncthreads();

  const int nk = K / BK;
  for (int kt = 0; kt < nk; ++kt) {
    #pragma unroll
    for (int kk = 0; kk < 2; ++kk) {
      short8 a[MR], b[NR];
      #pragma unroll
      for (int m = 0; m < MR; ++m) {
        int row = wr * WM + m * 16 + lr, col = kk * 32 + lg * 8;
        a[m] = *(const short8*)&As[row * 64 + (col ^ ((row & 7) << 3))];
      }
      #pragma unroll
      for (int n = 0; n < NR; ++n) {
        int row = wc * WN + n * 16 + lr, col = kk * 32 + lg * 8;
        b[n] = *(const short8*)&Bs[row * 64 + (col ^ ((row & 7) << 3))];
      }
      #pragma unroll
      for (int m = 0; m < MR; ++m)
        #pragma unroll
        for (int n = 0; n < NR; ++n)
          acc[m][n] = __builtin_amdgcn_mfma_f32_16x16x32_bf16(a[m], b[n], acc[m][n], 0, 0, 0);
    }
    if (kt + 1 < nk) {
      __syncthreads();
      dmaA((kt + 1) * BK); dmaB((kt + 1) * BK);
      __syncthreads();
    }
  }

  const float* biasz = bias ? (bias + (size_t)zb * biasZ) : nullptr;
  float* Cf = (float*)Cv;
  unsigned short* Cb = (unsigned short*)Cv;
  #pragma unroll
  for (int m = 0; m < MR; ++m) {
    #pragma unroll
    for (int i = 0; i < 4; ++i) {
      long row = row0 + wr * WM + m * 16 + lg * 4 + i;
      float rs = 1.f;
      if (rowscale) rs = 1.f / (sqrtf(rowscale[row]) + 1e-6f);
      float sq = 0.f;
      #pragma unroll
      for (int n = 0; n < NR; ++n) {
        long col = col0 + wc * WN + n * 16 + lr;
        float v = acc[m][n][i] * escale;
        size_t ci = (size_t)zb * cZ + (size_t)row * ldc + col;
        if constexpr (EPI == EPI_F32_RESID) {
          v += biasz[col] + rs * b2f(residb[(size_t)row * ldc + col]);
          Cf[ci] = v;
        } else if constexpr (EPI == EPI_BF16_SUMSQ) {
          if (biasz) v += biasz[col];
          Cb[ci] = f2bs(v);
          sq += v * v;
        } else {                      // EPI_BF16
          v *= rs;
          if (biasz) v += biasz[col];
          Cb[ci] = f2bs(v);
        }
      }
      if constexpr (EPI == EPI_BF16_SUMSQ) {
        #pragma unroll
        for (int off = 1; off < 16; off <<= 1) sq += __shfl_xor(sq, off);
        if (lr == 0) atomicAdd(&sumsq[row], sq);
      }
    }
  }
}

// -------- f32-A fused GEMM: C_bf16[M,768] = A_f32[M,K] @ B_bf16[768,K]^T + bias,
// + row sumsq. A staged raw f32 via global_load_lds (32KB), converted to bf16
// on fragment read with HW cvt_pk. Full-rank granule involution: granule g of
// row r lives at slot g ^ (r&15)  -> conflict-free b128 reads.
template<bool XCD1D>
__global__ __launch_bounds__(256, 3) void gemm_af32(
    const float* __restrict__ A, const short* __restrict__ B,
    unsigned short* __restrict__ C, const float* __restrict__ bias,
    float* __restrict__ sumsq, int K, int ncolb)
{
  constexpr int BM = 128, BN = 128, BK = 64, WM = 64, WN = 64, MR = 4, NR = 4;
  __shared__ __align__(16) float Asf[BM * BK];
  __shared__ __align__(16) short Bs[BN * BK];
  const int t = threadIdx.x;
  long bxc, byp;
  if constexpr (XCD1D) {
    int bid = blockIdx.x;
    int per = gridDim.x >> 3;
    int ppx = per / ncolb;
    int xcd = bid & 7, j = bid >> 3;
    byp = (long)xcd * ppx + j / ncolb;
    bxc = j % ncolb;
  } else {
    byp = blockIdx.x; bxc = blockIdx.y;
  }
  const long row0 = byp * BM;
  const long col0 = bxc * BN;
  const int wave = t >> 6, lane = t & 63;
  const int wr = wave >> 1, wc = wave & 1;
  const int lr = lane & 15, lg = lane >> 4;
  const int lrow8 = lane >> 3;
  const int lgran8 = (lane & 7) ^ lrow8;   // B-side (bf16) swizzle
  const int lrow4 = lane >> 4;             // A-side f32: 4 rows per 1KB chunk

  auto dmaAf = [&](int k0) {
    #pragma unroll
    for (int i = 0; i < 8; ++i) {
      int c = wave * 8 + i;              // 4-row chunk; row = c*4 + lrow4
      int lg16 = (lane & 15) ^ lrow4 ^ ((i & 3) << 2);
      gload16(A + (size_t)(row0 + c * 4 + lrow4) * K + k0 + lg16 * 4,
              &Asf[c * 256]);
    }
  };
  auto dmaB = [&](int k0) {
    #pragma unroll
    for (int i = 0; i < 4; ++i) {
      int c = wave * 4 + i;              // 8-row chunk
      gload16(B + (size_t)(col0 + c * 8 + lrow8) * K + k0 + lgran8 * 8,
              &Bs[c * 512]);
    }
  };

  const f32x4 zero4 = {0.f, 0.f, 0.f, 0.f};
  f32x4 acc[MR][NR];
  #pragma unroll
  for (int m = 0; m < MR; ++m)
    #pragma unroll
    for (int n = 0; n < NR; ++n) acc[m][n] = zero4;

  dmaAf(0); dmaB(0);
  __syncthreads();

  const int nk = K / BK;
  for (int kt = 0; kt < nk; ++kt) {
    #pragma unroll
    for (int kk = 0; kk < 2; ++kk) {
      short8 a[MR], b[NR];
      #pragma unroll
      for (int m = 0; m < MR; ++m) {
        int row = wr * WM + m * 16 + lr;   // row & 15 == lr
        int j0 = kk * 8 + lg * 2;          // f32 16B-granule index (2 per frag)
        float4 lo = *(const float4*)&Asf[row * 64 + ((j0 ^ lr) << 2)];
        float4 hi = *(const float4*)&Asf[row * 64 + (((j0 + 1) ^ lr) << 2)];
        union { short8 s; unsigned int u[4]; } U;
        U.u[0] = cvt2(lo.x, lo.y); U.u[1] = cvt2(lo.z, lo.w);
        U.u[2] = cvt2(hi.x, hi.y); U.u[3] = cvt2(hi.z, hi.w);
        a[m] = U.s;
      }
      #pragma unroll
      for (int n = 0; n < NR; ++n) {
        int row = wc * WN + n * 16 + lr, col = kk * 32 + lg * 8;
        b[n] = *(const short8*)&Bs[row * 64 + (col ^ ((row & 7) << 3))];
      }
      #pragma unroll
      for (int m = 0; m < MR; ++m)
        #pragma unroll
        for (int n = 0; n < NR; ++n)
          acc[m][n] = __builtin_amdgcn_mfma_f32_16x16x32_bf16(a[m], b[n], acc[m][n], 0, 0, 0);
    }
    if (kt + 1 < nk) {
      __syncthreads();
      dmaAf((kt + 1) * BK); dmaB((kt + 1) * BK);
      __syncthreads();
    }
  }

  #pragma unroll
  for (int m = 0; m < MR; ++m) {
    #pragma unroll
    for (int i = 0; i < 4; ++i) {
      long row = row0 + wr * WM + m * 16 + lg * 4 + i;
      float sq = 0.f;
      #pragma unroll
      for (int n = 0; n < NR; ++n) {
        long col = col0 + wc * WN + n * 16 + lr;
        float v = acc[m][n][i] + bias[col];
        C[(size_t)row * 768 + col] = f2bs(v);
        sq += v * v;
      }
      #pragma unroll
      for (int off = 1; off < 16; off <<= 1) sq += __shfl_xor(sq, off);
      if (lr == 0) atomicAdd(&sumsq[row], sq);
    }
  }
}

// all weight conversions in one dispatch
__global__ __launch_bounds__(256) void wconv_kernel(
    const float* __restrict__ Wx, const float* __restrict__ Wy,
    const float* __restrict__ ipw, const float* __restrict__ Wo,
    unsigned short* __restrict__ dWx, unsigned short* __restrict__ dWy,
    unsigned short* __restrict__ dWq, unsigned short* __restrict__ dWkT,
    unsigned short* __restrict__ dWv, unsigned short* __restrict__ dWo)
{
  long i = (long)blockIdx.x * 256 + threadIdx.x;
  if (i < 1179648) { dWx[i] = f2bs(Wx[i]); return; }
  i -= 1179648;
  if (i < 786432) { dWy[i] = f2bs(Wy[i]); return; }
  i -= 786432;
  if (i < 589824) { dWq[i] = f2bs(ipw[i]); return; }
  i -= 589824;
  if (i < 589824) {  // WkT[h][n][j] = Wk[h*64+j][n]
    int h = (int)(i / 49152), r = (int)(i % 49152);
    int nn = r >> 6, j = r & 63;
    dWkT[i] = f2bs(ipw[(size_t)(768 + h * 64 + j) * 768 + nn]);
    return;
  }
  i -= 589824;
  if (i < 589824) { dWv[i] = f2bs(ipw[2 * 589824 + i]); return; }
  i -= 589824;
  if (i < 589824) { dWo[i] = f2bs(Wo[i]); }
}

// Per-token fused: S = (qk . z)*invn -> softmax_w -> a = attn*invn -> u = a @ z
__global__ __launch_bounds__(256) void attn_kernel(
    const unsigned short* __restrict__ z, const unsigned short* __restrict__ qk,
    const float* __restrict__ ssy, unsigned short* __restrict__ u)
{
  __shared__ __align__(16) unsigned short zl[16 * 768];
  __shared__ __align__(16) unsigned short ql[12 * 768];
  __shared__ float sc[3][256];
  __shared__ float al[256];
  __shared__ float il[16];
  const int t = threadIdx.x;
  const long m = blockIdx.x;
  const int wv = t >> 6, lane = t & 63;
  const int lr = lane & 15, lg = lane >> 4;

  for (int s = t; s < 1536; s += 256) {
    int row = s / 96, g = s % 96;
    *(short8*)&zl[row * 768 + ((g ^ (row & 7)) << 3)] =
        *(const short8*)(z + m * 12288 + (size_t)s * 8);
  }
  for (int s = t; s < 1152; s += 256) {
    int row = s / 96, g = s % 96;
    *(short8*)&ql[row * 768 + ((g ^ (row & 7)) << 3)] =
        *(const short8*)(qk + m * 9216 + (size_t)s * 8);
  }
  if (t < 16) il[t] = 1.f / (sqrtf(ssy[m * 16 + t]) + 1e-6f);
  __syncthreads();

  f32x4 c = {0.f, 0.f, 0.f, 0.f};
  #pragma unroll
  for (int i = 0; i < 6; ++i) {
    int gb = wv * 24 + i * 4 + lg;
    short8 a = (lr < 12) ? *(const short8*)&ql[lr * 768 + ((gb ^ (lr & 7)) << 3)]
                         : short8{0, 0, 0, 0, 0, 0, 0, 0};
    short8 b = *(const short8*)&zl[lr * 768 + ((gb ^ (lr & 7)) << 3)];
    c = __builtin_amdgcn_mfma_f32_16x16x32_bf16(a, b, c, 0, 0, 0);
  }
  if (wv > 0) {
    #pragma unroll
    for (int i = 0; i < 4; ++i) sc[wv - 1][(lg * 4 + i) * 16 + lr] = c[i];
  }
  __syncthreads();
  if (wv == 0) {
    #pragma unroll
    for (int i = 0; i < 4; ++i) {
      int idx = (lg * 4 + i) * 16 + lr;
      float s = (c[i] + sc[0][idx] + sc[1][idx] + sc[2][idx]) * il[lr];
      float mx = s;
      #pragma unroll
      for (int off = 1; off < 16; off <<= 1) mx = fmaxf(mx, __shfl_xor(mx, off));
      float e = __expf(s - mx);
      float sum = e;
      #pragma unroll
      for (int off = 1; off < 16; off <<= 1) sum += __shfl_xor(sum, off);
      al[idx] = e / sum * il[lr];
    }
  }
  __syncthreads();

  for (int s = t; s < 1152; s += 256) {
    int h = s / 96, gd = s % 96;
    float acc[8] = {0.f, 0.f, 0.f, 0.f, 0.f, 0.f, 0.f, 0.f};
    #pragma unroll
    for (int w = 0; w < 16; ++w) {
      float aw = al[h * 16 + w];
      short8 zz = *(const short8*)&zl[w * 768 + ((gd ^ (w & 7)) << 3)];
      #pragma unroll
      for (int j = 0; j < 8; ++j) acc[j] += aw * b2f((unsigned short)zz[j]);
    }
    short8 o;
    #pragma unroll
    for (int j = 0; j < 8; ++j) o[j] = (short)f2bs(acc[j]);
    *(short8*)&u[m * 9216 + (size_t)s * 8] = o;
  }
}

__global__ __launch_bounds__(256) void ln_kernel(const float* __restrict__ R,
                                                 const float* __restrict__ w,
                                                 const float* __restrict__ b,
                                                 float* __restrict__ out) {
  const long row = blockIdx.x;
  const int t = threadIdx.x;
  const float* rr = R + row * 768;
  float v0 = rr[t], v1 = rr[t + 256], v2 = rr[t + 512];
  float s = v0 + v1 + v2;
  #pragma unroll
  for (int off = 1; off < 64; off <<= 1) s += __shfl_xor(s, off);
  __shared__ float ps[4];
  __shared__ float ps2[4];
  const int wave = t >> 6, lane = t & 63;
  if (lane == 0) ps[wave] = s;
  __syncthreads();
  const float mean = (ps[0] + ps[1] + ps[2] + ps[3]) * (1.f / 768.f);
  const float d0 = v0 - mean, d1 = v1 - mean, d2 = v2 - mean;
  float q = d0 * d0 + d1 * d1 + d2 * d2;
  #pragma unroll
  for (int off = 1; off < 64; off <<= 1) q += __shfl_xor(q, off);
  if (lane == 0) ps2[wave] = q;
  __syncthreads();
  const float var = (ps2[0] + ps2[1] + ps2[2] + ps2[3]) * (1.f / 768.f);
  const float rs = rsqrtf(var + 1e-6f);
  float* oo = out + row * 768;
  oo[t]       = d0 * rs * w[t]       + b[t];
  oo[t + 256] = d1 * rs * w[t + 256] + b[t + 256];
  oo[t + 512] = d2 * rs * w[t + 512] + b[t + 512];
}

extern "C" void kernel_launch(void* const* d_in, const int* in_sizes, int n_in,
                              void* d_out, int out_size, void* d_ws, size_t ws_size,
                              hipStream_t stream) {
  const float* x   = (const float*)d_in[0];   // (8,1024,1536)
  const float* y   = (const float*)d_in[1];   // (8,16384,1024)
  const float* Wx  = (const float*)d_in[2];   // (768,1536)
  const float* bx  = (const float*)d_in[3];
  const float* Wy  = (const float*)d_in[4];   // (768,1024)
  const float* by  = (const float*)d_in[5];
  const float* ipw = (const float*)d_in[6];   // (2304,768)
  const float* ipb = (const float*)d_in[7];
  const float* Wo  = (const float*)d_in[8];   // (768,768)
  const float* ob  = (const float*)d_in[9];
  const float* lnw = (const float*)d_in[10];
  const float* lnb = (const float*)d_in[11];
  float* out = (float*)d_out;

  char* ws = (char*)d_ws;
  size_t off = 0;
  auto alloc = [&](size_t bytes) {
    void* p = ws + off;
    off += (bytes + 4095) & ~(size_t)4095;
    return p;
  };
  unsigned short* Wx_b  = (unsigned short*)alloc(768L * 1536 * 2);
  unsigned short* Wy_b  = (unsigned short*)alloc(768L * 1024 * 2);
  unsigned short* Wq_b  = (unsigned short*)alloc(768L * 768 * 2);
  unsigned short* WkT_b = (unsigned short*)alloc(768L * 768 * 2);
  unsigned short* Wv_b  = (unsigned short*)alloc(768L * 768 * 2);
  unsigned short* Wo_b  = (unsigned short*)alloc(768L * 768 * 2);
  float* ssx = (float*)alloc(8192L * 4);
  float* ssy = (float*)alloc(131072L * 4);
  unsigned short* z_b  = (unsigned short*)alloc(131072L * 768 * 2);
  unsigned short* xq_b = (unsigned short*)alloc(8192L * 768 * 2);
  char* reg = (char*)alloc(134217728L * 2);    // 256 MB scratch region
  unsigned short* q_b  = (unsigned short*)(reg + 25165824);       // 12.6 MB
  unsigned short* qk_b = (unsigned short*)(reg + 37748736);       // 151 MB (also u)
  unsigned short* o_b  = (unsigned short*)(reg + 188743680);      // 12.6 MB
  float*          r_f  = (float*)(reg + 201326592);               // 25.2 MB
  (void)ws_size; (void)in_sizes; (void)n_in; (void)out_size;

  hipMemsetAsync(ssx, 0, 8192L * 4, stream);
  hipMemsetAsync(ssy, 0, 131072L * 4, stream);

  // all weights -> bf16 in one dispatch (4325376 elems)
  wconv_kernel<<<16896, 256, 0, stream>>>(Wx, Wy, ipw, Wo,
                                          Wx_b, Wy_b, Wq_b, WkT_b, Wv_b, Wo_b);

  // z = y @ Wy^T + by (bf16 + sumsq), f32 A fused, XCD-contiguous panels
  gemm_af32<true><<<6144, 256, 0, stream>>>(
      y, (const short*)Wy_b, z_b, by, ssy, 1024, 6);

  // xq_raw = x @ Wx^T + bx (bf16, UNSCALED, + sumsq); scale folded downstream
  gemm_af32<false><<<dim3(64, 6, 1), 256, 0, stream>>>(
      x, (const short*)Wx_b, xq_b, bx, ssx, 1536, 0);

  // q = rs[m]*(xq_raw @ Wq^T) + bq   (rowscale folded into epilogue)
  gemm_bt<128, 128, EPI_BF16, false><<<dim3(64, 6, 1), 256, 0, stream>>>(
      (const short*)xq_b, (const short*)Wq_b, q_b, ipb, nullptr, nullptr, ssx,
      768, 768, 768, 768, 1.f, 0, 0, 0, 0, 0);

  // qk[m,h,:] = scale * q[m,h*64:+64] @ WkT[h]   (bk dropped: softmax-invariant)
  gemm_bt<128, 128, EPI_BF16, false><<<dim3(64, 6, 12), 256, 0, stream>>>(
      (const short*)q_b, (const short*)WkT_b, qk_b, nullptr, nullptr, nullptr, nullptr,
      768, 64, 9216, 64, 0.125f, 64, 49152, 768, 0, 0);

  // fused scores/softmax/u  (u overwrites qk slice per token)
  attn_kernel<<<8192, 256, 0, stream>>>(z_b, qk_b, ssy, qk_b);

  // o[:,h*64:+64] = u[:,h,:] @ Wv_h^T + bv_h
  gemm_bt<128, 64, EPI_BF16, false><<<dim3(64, 1, 12), 256, 0, stream>>>(
      (const short*)qk_b, (const short*)Wv_b, o_b, ipb + 1536, nullptr, nullptr, nullptr,
      9216, 768, 768, 768, 1.f, 768, 49152, 64, 64, 0);

  // r = o @ out_w^T + out_b + rs[m]*xq_raw   (residual row-scale in epilogue)
  gemm_bt<128, 128, EPI_F32_RESID, false><<<dim3(64, 6, 1), 256, 0, stream>>>(
      (const short*)o_b, (const short*)Wo_b, r_f, ob, xq_b, nullptr, ssx,
      768, 768, 768, 768, 1.f, 0, 0, 0, 0, 0);

  ln_kernel<<<8192, 256, 0, stream>>>(r_f, lnw, lnb, out);
}